// Round 1
// baseline (12068.095 us; speedup 1.0000x reference)
//
#include <hip/hip_runtime.h>
#include <hip/hip_bf16.h>
#include <math.h>

#define B_ 8
#define S_ 1024
#define D_ 768
#define H_ 12
#define DH_ 64
#define FF_ 3072
#define E_ 8
#define CAP_ 2048
#define T_ (B_ * S_)

// ---------------- generic tiled fp32 GEMM: C[M,N] = A[M,K] @ W[K,N] + bias, opt GELU
#define BM 64
#define BN 64
#define BK 16

__global__ __launch_bounds__(256) void gemm_bias_kernel(
    const float* __restrict__ A, const float* __restrict__ W,
    const float* __restrict__ bias, float* __restrict__ C,
    int M, int N, int K, int apply_gelu)
{
    __shared__ float As[BK][BM + 1];
    __shared__ float Bs[BK][BN + 1];
    const int bx = blockIdx.x;     // N tile
    const int by = blockIdx.y;     // M tile
    const int tid = threadIdx.x;
    const int tx = tid & 15;       // 0..15 -> cols
    const int ty = tid >> 4;       // 0..15 -> rows
    const int row0 = by * BM, col0 = bx * BN;
    float acc[4][4] = {};
    for (int k0 = 0; k0 < K; k0 += BK) {
        #pragma unroll
        for (int i = 0; i < 4; i++) {
            int idx = tid + i * 256;           // 0..1023
            int r = idx >> 4;                  // /BK
            int kk = idx & 15;
            As[kk][r] = A[(size_t)(row0 + r) * K + (k0 + kk)];
        }
        #pragma unroll
        for (int i = 0; i < 4; i++) {
            int idx = tid + i * 256;
            int kk = idx >> 6;                 // /BN
            int c = idx & 63;
            Bs[kk][c] = W[(size_t)(k0 + kk) * N + (col0 + c)];
        }
        __syncthreads();
        #pragma unroll
        for (int kk = 0; kk < BK; kk++) {
            float a[4], b[4];
            #pragma unroll
            for (int i = 0; i < 4; i++) a[i] = As[kk][ty * 4 + i];
            #pragma unroll
            for (int j = 0; j < 4; j++) b[j] = Bs[kk][tx * 4 + j];
            #pragma unroll
            for (int i = 0; i < 4; i++)
                #pragma unroll
                for (int j = 0; j < 4; j++) acc[i][j] += a[i] * b[j];
        }
        __syncthreads();
    }
    #pragma unroll
    for (int i = 0; i < 4; i++) {
        int r = row0 + ty * 4 + i;
        #pragma unroll
        for (int j = 0; j < 4; j++) {
            int c = col0 + tx * 4 + j;
            float v = acc[i][j] + bias[c];
            if (apply_gelu) v = 0.5f * v * (1.0f + erff(v * 0.70710678118654752f));
            C[(size_t)r * N + c] = v;
        }
    }
}

// ---------------- attention: one block per (b,h,s) query row
__global__ __launch_bounds__(256) void attn_kernel(
    const float* __restrict__ q, const float* __restrict__ k,
    const float* __restrict__ v, const float* __restrict__ mask,
    float* __restrict__ ctx)
{
    const int s = blockIdx.x, h = blockIdx.y, b = blockIdx.z;
    const int tid = threadIdx.x;
    __shared__ float sc[S_];
    __shared__ float qs[DH_];
    __shared__ float red[256];
    const size_t base = (size_t)b * S_ * D_ + (size_t)h * DH_;
    if (tid < DH_) qs[tid] = q[base + (size_t)s * D_ + tid];
    __syncthreads();
    for (int t = tid; t < S_; t += 256) {
        const float* kp = k + base + (size_t)t * D_;
        float acc = 0.f;
        #pragma unroll
        for (int d = 0; d < DH_; d++) acc += qs[d] * kp[d];
        sc[t] = acc * 0.125f + mask[b * S_ + t];
    }
    __syncthreads();
    // max
    float m = -1e30f;
    for (int t = tid; t < S_; t += 256) m = fmaxf(m, sc[t]);
    red[tid] = m; __syncthreads();
    for (int off = 128; off > 0; off >>= 1) {
        if (tid < off) red[tid] = fmaxf(red[tid], red[tid + off]);
        __syncthreads();
    }
    m = red[0]; __syncthreads();
    // exp + sum
    float lsum = 0.f;
    for (int t = tid; t < S_; t += 256) { float e = expf(sc[t] - m); sc[t] = e; lsum += e; }
    red[tid] = lsum; __syncthreads();
    for (int off = 128; off > 0; off >>= 1) {
        if (tid < off) red[tid] += red[tid + off];
        __syncthreads();
    }
    const float inv = 1.0f / red[0];
    // ctx: dh = tid&63, 4 partial chunks over t
    const int dh = tid & 63, part = tid >> 6;
    float accv = 0.f;
    for (int t = part * 256; t < part * 256 + 256; t++)
        accv += sc[t] * v[base + (size_t)t * D_ + dh];
    __syncthreads();
    red[tid] = accv;
    __syncthreads();
    if (tid < 64) {
        float r = red[tid] + red[tid + 64] + red[tid + 128] + red[tid + 192];
        ctx[((size_t)b * S_ + s) * D_ + h * DH_ + dh] = r * inv;
    }
}

// ---------------- out[t] = LN(x[t] + y[t]) * g + b  (per-token block of 256)
__global__ __launch_bounds__(256) void add_ln_kernel(
    const float* __restrict__ x, const float* __restrict__ y,
    const float* __restrict__ g, const float* __restrict__ bb,
    float* __restrict__ out)
{
    const int t = blockIdx.x;
    const int tid = threadIdx.x;
    __shared__ float red[256];
    float vals[3];
    float lsum = 0.f;
    #pragma unroll
    for (int i = 0; i < 3; i++) {
        int c = tid + i * 256;
        float v = x[(size_t)t * D_ + c] + y[(size_t)t * D_ + c];
        vals[i] = v; lsum += v;
    }
    red[tid] = lsum; __syncthreads();
    for (int off = 128; off > 0; off >>= 1) { if (tid < off) red[tid] += red[tid + off]; __syncthreads(); }
    const float mu = red[0] * (1.0f / D_);
    __syncthreads();
    float lvar = 0.f;
    #pragma unroll
    for (int i = 0; i < 3; i++) { float d = vals[i] - mu; lvar += d * d; }
    red[tid] = lvar; __syncthreads();
    for (int off = 128; off > 0; off >>= 1) { if (tid < off) red[tid] += red[tid + off]; __syncthreads(); }
    const float rstd = rsqrtf(red[0] * (1.0f / D_) + 1e-12f);
    #pragma unroll
    for (int i = 0; i < 3; i++) {
        int c = tid + i * 256;
        out[(size_t)t * D_ + c] = (vals[i] - mu) * rstd * g[c] + bb[c];
    }
}

// ---------------- router: 1 wave per token
__global__ __launch_bounds__(64) void router_kernel(
    const float* __restrict__ att, const float* __restrict__ Wr,
    const float* __restrict__ br, float* __restrict__ gate, int* __restrict__ eidx)
{
    const int t = blockIdx.x;
    const int lane = threadIdx.x;
    float lg[E_] = {};
    for (int d = lane; d < D_; d += 64) {
        float xv = att[(size_t)t * D_ + d];
        #pragma unroll
        for (int e = 0; e < E_; e++) lg[e] += xv * Wr[d * E_ + e];
    }
    #pragma unroll
    for (int off = 32; off > 0; off >>= 1)
        #pragma unroll
        for (int e = 0; e < E_; e++) lg[e] += __shfl_down(lg[e], off);
    if (lane == 0) {
        float mx = -1e30f; int mi = 0;
        #pragma unroll
        for (int e = 0; e < E_; e++) {
            lg[e] += br[e];
            if (lg[e] > mx) { mx = lg[e]; mi = e; }
        }
        float ssum = 0.f;
        #pragma unroll
        for (int e = 0; e < E_; e++) ssum += expf(lg[e] - mx);
        gate[t] = 1.0f / ssum;   // max softmax prob
        eidx[t] = mi;
    }
}

// ---------------- position-within-expert scan (single block, segmented)
__global__ __launch_bounds__(256) void pos_scan_kernel(
    const int* __restrict__ eidx, const float* __restrict__ gate,
    int* __restrict__ pos, float* __restrict__ scale)
{
    __shared__ int cnt[256][E_];
    const int tid = threadIdx.x;
    const int start = tid * (T_ / 256);
    int lc[E_] = {};
    for (int i = 0; i < T_ / 256; i++) lc[eidx[start + i]]++;
    #pragma unroll
    for (int e = 0; e < E_; e++) cnt[tid][e] = lc[e];
    __syncthreads();
    if (tid < E_) {
        int run = 0;
        for (int i = 0; i < 256; i++) { int c = cnt[i][tid]; cnt[i][tid] = run; run += c; }
    }
    __syncthreads();
    int off[E_];
    #pragma unroll
    for (int e = 0; e < E_; e++) off[e] = cnt[tid][e];
    for (int i = 0; i < T_ / 256; i++) {
        int tk = start + i;
        int e = eidx[tk];
        int p = off[e]++;
        bool keep = p < CAP_;
        pos[tk] = p < CAP_ - 1 ? p : CAP_ - 1;
        scale[tk] = keep ? gate[tk] : 0.0f;
    }
}

// ---------------- scatter kept tokens into per-expert buffers
__global__ __launch_bounds__(256) void scatter_kernel(
    const float* __restrict__ att, const int* __restrict__ eidx,
    const int* __restrict__ pos, const float* __restrict__ scale,
    float* __restrict__ buf)
{
    const int t = blockIdx.x;
    if (scale[t] == 0.0f) return;   // dropped (gate>0 always)
    const int tid = threadIdx.x;
    const float* src = att + (size_t)t * D_;
    float* dst = buf + ((size_t)eidx[t] * CAP_ + pos[t]) * D_;
    for (int i = tid; i < D_; i += 256) dst[i] = src[i];
}

// ---------------- gather + residual + final LN
__global__ __launch_bounds__(256) void final_ln_kernel(
    const float* __restrict__ att, const float* __restrict__ y,
    const int* __restrict__ eidx, const int* __restrict__ pos,
    const float* __restrict__ scale,
    const float* __restrict__ g, const float* __restrict__ bb,
    float* __restrict__ out)
{
    const int t = blockIdx.x;
    const int tid = threadIdx.x;
    __shared__ float red[256];
    const float sc = scale[t];
    const float* yrow = y + ((size_t)eidx[t] * CAP_ + pos[t]) * D_;
    float vals[3];
    float lsum = 0.f;
    #pragma unroll
    for (int i = 0; i < 3; i++) {
        int c = tid + i * 256;
        float v = att[(size_t)t * D_ + c] + yrow[c] * sc;
        vals[i] = v; lsum += v;
    }
    red[tid] = lsum; __syncthreads();
    for (int off = 128; off > 0; off >>= 1) { if (tid < off) red[tid] += red[tid + off]; __syncthreads(); }
    const float mu = red[0] * (1.0f / D_);
    __syncthreads();
    float lvar = 0.f;
    #pragma unroll
    for (int i = 0; i < 3; i++) { float d = vals[i] - mu; lvar += d * d; }
    red[tid] = lvar; __syncthreads();
    for (int off = 128; off > 0; off >>= 1) { if (tid < off) red[tid] += red[tid + off]; __syncthreads(); }
    const float rstd = rsqrtf(red[0] * (1.0f / D_) + 1e-12f);
    #pragma unroll
    for (int i = 0; i < 3; i++) {
        int c = tid + i * 256;
        out[(size_t)t * D_ + c] = (vals[i] - mu) * rstd * g[c] + bb[c];
    }
}

extern "C" void kernel_launch(void* const* d_in, const int* in_sizes, int n_in,
                              void* d_out, int out_size, void* d_ws, size_t ws_size,
                              hipStream_t stream) {
    const float* x     = (const float*)d_in[0];   // [B,S,D]
    const float* mask  = (const float*)d_in[1];   // [B,1,1,S]
    const float* Wq    = (const float*)d_in[2];
    const float* bq    = (const float*)d_in[3];
    const float* Wk    = (const float*)d_in[4];
    const float* bk    = (const float*)d_in[5];
    const float* Wv    = (const float*)d_in[6];
    const float* bv    = (const float*)d_in[7];
    const float* Wo    = (const float*)d_in[8];
    const float* bo    = (const float*)d_in[9];
    const float* ln1g  = (const float*)d_in[10];
    const float* ln1b  = (const float*)d_in[11];
    const float* Wr    = (const float*)d_in[12];
    const float* br    = (const float*)d_in[13];
    const float* W1    = (const float*)d_in[14];  // [E,D,FF]
    const float* b1    = (const float*)d_in[15];  // [E,FF]
    const float* W2    = (const float*)d_in[16];  // [E,FF,D]
    const float* b2    = (const float*)d_in[17];  // [E,D]
    const float* ln2g  = (const float*)d_in[18];
    const float* ln2b  = (const float*)d_in[19];
    float* out = (float*)d_out;

    float* ws = (float*)d_ws;
    const size_t TD = (size_t)T_ * D_;                 // 6291456
    float* q_buf   = ws;                               // [T,D]  (later reused by y)
    float* k_buf   = ws + TD;                          // [T,D]
    float* v_buf   = ws + 2 * TD;                      // [T,D]
    float* ctx_buf = ws + 3 * TD;                      // [T,D]
    float* att_buf = ws + 4 * TD;                      // [T,D]
    float* gate_b  = ws + 5 * TD;                      // [T]
    int*   eidx_b  = (int*)(ws + 5 * TD + T_);         // [T]
    int*   pos_b   = (int*)(ws + 5 * TD + 2 * T_);     // [T]
    float* scale_b = ws + 5 * TD + 3 * T_;             // [T]
    float* buf_b   = ws + 5 * TD + 4 * T_;             // [E,CAP,D] = 12582912
    float* h_buf   = buf_b + (size_t)E_ * CAP_ * D_;   // [CAP,FF] per-expert = 6291456
    float* proj_b  = q_buf;                            // reuse q region for ctx@Wo
    float* y_buf   = ws;                               // [E,CAP,D] reuses q+k regions

    dim3 blk(256);
    // QKV projections
    gemm_bias_kernel<<<dim3(D_ / BN, T_ / BM), blk, 0, stream>>>(x, Wq, bq, q_buf, T_, D_, D_, 0);
    gemm_bias_kernel<<<dim3(D_ / BN, T_ / BM), blk, 0, stream>>>(x, Wk, bk, k_buf, T_, D_, D_, 0);
    gemm_bias_kernel<<<dim3(D_ / BN, T_ / BM), blk, 0, stream>>>(x, Wv, bv, v_buf, T_, D_, D_, 0);
    // attention
    attn_kernel<<<dim3(S_, H_, B_), blk, 0, stream>>>(q_buf, k_buf, v_buf, mask, ctx_buf);
    // output projection (into q region; q is dead)
    gemm_bias_kernel<<<dim3(D_ / BN, T_ / BM), blk, 0, stream>>>(ctx_buf, Wo, bo, proj_b, T_, D_, D_, 0);
    // att_out = LN1(x + proj)
    add_ln_kernel<<<dim3(T_), blk, 0, stream>>>(x, proj_b, ln1g, ln1b, att_buf);
    // routing
    router_kernel<<<dim3(T_), dim3(64), 0, stream>>>(att_buf, Wr, br, gate_b, eidx_b);
    pos_scan_kernel<<<dim3(1), blk, 0, stream>>>(eidx_b, gate_b, pos_b, scale_b);
    // expert buffers
    hipMemsetAsync(buf_b, 0, (size_t)E_ * CAP_ * D_ * sizeof(float), stream);
    scatter_kernel<<<dim3(T_), blk, 0, stream>>>(att_buf, eidx_b, pos_b, scale_b, buf_b);
    // expert FFNs (h buffer reused per expert; y into q/k region which is dead)
    for (int e = 0; e < E_; e++) {
        const float* W1e = W1 + (size_t)e * D_ * FF_;
        const float* b1e = b1 + (size_t)e * FF_;
        const float* W2e = W2 + (size_t)e * FF_ * D_;
        const float* b2e = b2 + (size_t)e * D_;
        float* bufe = buf_b + (size_t)e * CAP_ * D_;
        float* ye   = y_buf + (size_t)e * CAP_ * D_;
        gemm_bias_kernel<<<dim3(FF_ / BN, CAP_ / BM), blk, 0, stream>>>(bufe, W1e, b1e, h_buf, CAP_, FF_, D_, 1);
        gemm_bias_kernel<<<dim3(D_ / BN, CAP_ / BM), blk, 0, stream>>>(h_buf, W2e, b2e, ye, CAP_, D_, FF_, 0);
    }
    // gather + residual + LN2
    final_ln_kernel<<<dim3(T_), blk, 0, stream>>>(att_buf, y_buf, eidx_b, pos_b, scale_b, ln2g, ln2b, out);
}

// Round 2
// 6117.776 us; speedup vs baseline: 1.9726x; 1.9726x over previous
//
#include <hip/hip_runtime.h>
#include <hip/hip_bf16.h>
#include <math.h>

#define B_ 8
#define S_ 1024
#define D_ 768
#define H_ 12
#define DH_ 64
#define FF_ 3072
#define E_ 8
#define CAP_ 2048
#define T_ (B_ * S_)

// ---------------- generic tiled fp32 GEMM: C[M,N] = A[M,K] @ W[K,N] + bias, opt GELU
#define BM 64
#define BN 64
#define BK 16

__global__ __launch_bounds__(256) void gemm_bias_kernel(
    const float* __restrict__ A, const float* __restrict__ W,
    const float* __restrict__ bias, float* __restrict__ C,
    int M, int N, int K, int apply_gelu)
{
    __shared__ float As[BK][BM + 1];
    __shared__ float Bs[BK][BN + 1];
    const int bx = blockIdx.x;     // N tile
    const int by = blockIdx.y;     // M tile
    const int tid = threadIdx.x;
    const int tx = tid & 15;       // 0..15 -> cols
    const int ty = tid >> 4;       // 0..15 -> rows
    const int row0 = by * BM, col0 = bx * BN;
    float acc[4][4] = {};
    for (int k0 = 0; k0 < K; k0 += BK) {
        #pragma unroll
        for (int i = 0; i < 4; i++) {
            int idx = tid + i * 256;           // 0..1023
            int r = idx >> 4;                  // /BK
            int kk = idx & 15;
            As[kk][r] = A[(size_t)(row0 + r) * K + (k0 + kk)];
        }
        #pragma unroll
        for (int i = 0; i < 4; i++) {
            int idx = tid + i * 256;
            int kk = idx >> 6;                 // /BN
            int c = idx & 63;
            Bs[kk][c] = W[(size_t)(k0 + kk) * N + (col0 + c)];
        }
        __syncthreads();
        #pragma unroll
        for (int kk = 0; kk < BK; kk++) {
            float a[4], b[4];
            #pragma unroll
            for (int i = 0; i < 4; i++) a[i] = As[kk][ty * 4 + i];
            #pragma unroll
            for (int j = 0; j < 4; j++) b[j] = Bs[kk][tx * 4 + j];
            #pragma unroll
            for (int i = 0; i < 4; i++)
                #pragma unroll
                for (int j = 0; j < 4; j++) acc[i][j] += a[i] * b[j];
        }
        __syncthreads();
    }
    #pragma unroll
    for (int i = 0; i < 4; i++) {
        int r = row0 + ty * 4 + i;
        #pragma unroll
        for (int j = 0; j < 4; j++) {
            int c = col0 + tx * 4 + j;
            float v = acc[i][j] + bias[c];
            if (apply_gelu) v = 0.5f * v * (1.0f + erff(v * 0.70710678118654752f));
            C[(size_t)r * N + c] = v;
        }
    }
}

// ---------------- flash-style attention: one block per (b, h, 64-query tile)
#define AS 68   // LDS row stride (floats): 16B-aligned rows, low bank conflicts

__global__ __launch_bounds__(256) void flash_attn_kernel(
    const float* __restrict__ q, const float* __restrict__ k,
    const float* __restrict__ v, const float* __restrict__ mask,
    float* __restrict__ ctx)
{
    __shared__ float Qs[64 * AS];
    __shared__ float Ks[64 * AS];
    __shared__ float VsT[64 * AS];   // VsT[c][k] = V[k][c]
    __shared__ float Ps[64 * AS];
    const int qt = blockIdx.x, h = blockIdx.y, b = blockIdx.z;
    const int tid = threadIdx.x;
    const int tx = tid & 15, ty = tid >> 4;
    const int q0 = qt * 64;
    const size_t headbase = (size_t)b * S_ * D_ + (size_t)h * DH_;

    // stage Q tile (row-major, float4, coalesced)
    #pragma unroll
    for (int i = 0; i < 4; i++) {
        int idx = i * 256 + tid;           // 0..1023
        int r = idx >> 4, fc = idx & 15;
        *(float4*)&Qs[r * AS + fc * 4] =
            *(const float4*)&q[headbase + (size_t)(q0 + r) * D_ + fc * 4];
    }

    float O[4][4] = {};
    float mrun[4], lrun[4];
    #pragma unroll
    for (int i = 0; i < 4; i++) { mrun[i] = -1e30f; lrun[i] = 0.f; }

    for (int kt = 0; kt < S_ / 64; kt++) {
        const int k0 = kt * 64;
        __syncthreads();   // protect Ks/VsT/Ps from previous iteration's readers
        // stage K tile row-major (float4)
        #pragma unroll
        for (int i = 0; i < 4; i++) {
            int idx = i * 256 + tid;
            int r = idx >> 4, fc = idx & 15;
            *(float4*)&Ks[r * AS + fc * 4] =
                *(const float4*)&k[headbase + (size_t)(k0 + r) * D_ + fc * 4];
        }
        // stage V transposed (coalesced global reads, scalar LDS writes)
        #pragma unroll
        for (int i = 0; i < 16; i++) {
            int idx = i * 256 + tid;
            int key = idx >> 6, d = idx & 63;
            VsT[d * AS + key] = v[headbase + (size_t)(k0 + key) * D_ + d];
        }
        __syncthreads();

        // S tile = Q @ K^T ; thread owns rows {4ty+i}, key cols {tx+16j}
        float acc[4][4] = {};
        #pragma unroll 4
        for (int d0 = 0; d0 < DH_; d0 += 4) {
            float4 a4[4], b4[4];
            #pragma unroll
            for (int i = 0; i < 4; i++) a4[i] = *(float4*)&Qs[(ty * 4 + i) * AS + d0];
            #pragma unroll
            for (int j = 0; j < 4; j++) b4[j] = *(float4*)&Ks[(tx + 16 * j) * AS + d0];
            #pragma unroll
            for (int i = 0; i < 4; i++)
                #pragma unroll
                for (int j = 0; j < 4; j++)
                    acc[i][j] += a4[i].x * b4[j].x + a4[i].y * b4[j].y
                               + a4[i].z * b4[j].z + a4[i].w * b4[j].w;
        }
        float mk[4];
        #pragma unroll
        for (int j = 0; j < 4; j++) mk[j] = mask[b * S_ + k0 + tx + 16 * j];

        // online softmax update per owned row
        #pragma unroll
        for (int i = 0; i < 4; i++) {
            float s[4];
            float rmax = -1e30f;
            #pragma unroll
            for (int j = 0; j < 4; j++) {
                s[j] = acc[i][j] * 0.125f + mk[j];
                rmax = fmaxf(rmax, s[j]);
            }
            #pragma unroll
            for (int off = 1; off < 16; off <<= 1) rmax = fmaxf(rmax, __shfl_xor(rmax, off));
            const float mnew = fmaxf(mrun[i], rmax);
            const float alpha = __expf(mrun[i] - mnew);
            float rsum = 0.f;
            #pragma unroll
            for (int j = 0; j < 4; j++) {
                float p = __expf(s[j] - mnew);
                Ps[(ty * 4 + i) * AS + tx + 16 * j] = p;
                rsum += p;
            }
            #pragma unroll
            for (int off = 1; off < 16; off <<= 1) rsum += __shfl_xor(rsum, off);
            lrun[i] = lrun[i] * alpha + rsum;
            mrun[i] = mnew;
            #pragma unroll
            for (int j = 0; j < 4; j++) O[i][j] *= alpha;
        }
        __syncthreads();

        // O += P @ V ; VsT rows are V columns -> float4 dot over k
        #pragma unroll 4
        for (int c0 = 0; c0 < 64; c0 += 4) {
            float4 a4[4], b4[4];
            #pragma unroll
            for (int i = 0; i < 4; i++) a4[i] = *(float4*)&Ps[(ty * 4 + i) * AS + c0];
            #pragma unroll
            for (int j = 0; j < 4; j++) b4[j] = *(float4*)&VsT[(tx + 16 * j) * AS + c0];
            #pragma unroll
            for (int i = 0; i < 4; i++)
                #pragma unroll
                for (int j = 0; j < 4; j++)
                    O[i][j] += a4[i].x * b4[j].x + a4[i].y * b4[j].y
                             + a4[i].z * b4[j].z + a4[i].w * b4[j].w;
        }
    }

    #pragma unroll
    for (int i = 0; i < 4; i++) {
        const float invl = 1.0f / lrun[i];
        #pragma unroll
        for (int j = 0; j < 4; j++)
            ctx[headbase + (size_t)(q0 + ty * 4 + i) * D_ + tx + 16 * j] = O[i][j] * invl;
    }
}

// ---------------- out[t] = LN(x[t] + y[t]) * g + b  (per-token block of 256)
__global__ __launch_bounds__(256) void add_ln_kernel(
    const float* __restrict__ x, const float* __restrict__ y,
    const float* __restrict__ g, const float* __restrict__ bb,
    float* __restrict__ out)
{
    const int t = blockIdx.x;
    const int tid = threadIdx.x;
    __shared__ float red[256];
    float vals[3];
    float lsum = 0.f;
    #pragma unroll
    for (int i = 0; i < 3; i++) {
        int c = tid + i * 256;
        float v = x[(size_t)t * D_ + c] + y[(size_t)t * D_ + c];
        vals[i] = v; lsum += v;
    }
    red[tid] = lsum; __syncthreads();
    for (int off = 128; off > 0; off >>= 1) { if (tid < off) red[tid] += red[tid + off]; __syncthreads(); }
    const float mu = red[0] * (1.0f / D_);
    __syncthreads();
    float lvar = 0.f;
    #pragma unroll
    for (int i = 0; i < 3; i++) { float d = vals[i] - mu; lvar += d * d; }
    red[tid] = lvar; __syncthreads();
    for (int off = 128; off > 0; off >>= 1) { if (tid < off) red[tid] += red[tid + off]; __syncthreads(); }
    const float rstd = rsqrtf(red[0] * (1.0f / D_) + 1e-12f);
    #pragma unroll
    for (int i = 0; i < 3; i++) {
        int c = tid + i * 256;
        out[(size_t)t * D_ + c] = (vals[i] - mu) * rstd * g[c] + bb[c];
    }
}

// ---------------- router: 1 wave per token
__global__ __launch_bounds__(64) void router_kernel(
    const float* __restrict__ att, const float* __restrict__ Wr,
    const float* __restrict__ br, float* __restrict__ gate, int* __restrict__ eidx)
{
    const int t = blockIdx.x;
    const int lane = threadIdx.x;
    float lg[E_] = {};
    for (int d = lane; d < D_; d += 64) {
        float xv = att[(size_t)t * D_ + d];
        #pragma unroll
        for (int e = 0; e < E_; e++) lg[e] += xv * Wr[d * E_ + e];
    }
    #pragma unroll
    for (int off = 32; off > 0; off >>= 1)
        #pragma unroll
        for (int e = 0; e < E_; e++) lg[e] += __shfl_down(lg[e], off);
    if (lane == 0) {
        float mx = -1e30f; int mi = 0;
        #pragma unroll
        for (int e = 0; e < E_; e++) {
            lg[e] += br[e];
            if (lg[e] > mx) { mx = lg[e]; mi = e; }
        }
        float ssum = 0.f;
        #pragma unroll
        for (int e = 0; e < E_; e++) ssum += expf(lg[e] - mx);
        gate[t] = 1.0f / ssum;   // max softmax prob
        eidx[t] = mi;
    }
}

// ---------------- position-within-expert scan (single block, segmented)
__global__ __launch_bounds__(256) void pos_scan_kernel(
    const int* __restrict__ eidx, const float* __restrict__ gate,
    int* __restrict__ pos, float* __restrict__ scale)
{
    __shared__ int cnt[256][E_];
    const int tid = threadIdx.x;
    const int start = tid * (T_ / 256);
    int lc[E_] = {};
    for (int i = 0; i < T_ / 256; i++) lc[eidx[start + i]]++;
    #pragma unroll
    for (int e = 0; e < E_; e++) cnt[tid][e] = lc[e];
    __syncthreads();
    if (tid < E_) {
        int run = 0;
        for (int i = 0; i < 256; i++) { int c = cnt[i][tid]; cnt[i][tid] = run; run += c; }
    }
    __syncthreads();
    int off[E_];
    #pragma unroll
    for (int e = 0; e < E_; e++) off[e] = cnt[tid][e];
    for (int i = 0; i < T_ / 256; i++) {
        int tk = start + i;
        int e = eidx[tk];
        int p = off[e]++;
        bool keep = p < CAP_;
        pos[tk] = p < CAP_ - 1 ? p : CAP_ - 1;
        scale[tk] = keep ? gate[tk] : 0.0f;
    }
}

// ---------------- scatter kept tokens into per-expert buffers
__global__ __launch_bounds__(256) void scatter_kernel(
    const float* __restrict__ att, const int* __restrict__ eidx,
    const int* __restrict__ pos, const float* __restrict__ scale,
    float* __restrict__ buf)
{
    const int t = blockIdx.x;
    if (scale[t] == 0.0f) return;   // dropped (gate>0 always)
    const int tid = threadIdx.x;
    const float* src = att + (size_t)t * D_;
    float* dst = buf + ((size_t)eidx[t] * CAP_ + pos[t]) * D_;
    for (int i = tid; i < D_; i += 256) dst[i] = src[i];
}

// ---------------- gather + residual + final LN
__global__ __launch_bounds__(256) void final_ln_kernel(
    const float* __restrict__ att, const float* __restrict__ y,
    const int* __restrict__ eidx, const int* __restrict__ pos,
    const float* __restrict__ scale,
    const float* __restrict__ g, const float* __restrict__ bb,
    float* __restrict__ out)
{
    const int t = blockIdx.x;
    const int tid = threadIdx.x;
    __shared__ float red[256];
    const float sc = scale[t];
    const float* yrow = y + ((size_t)eidx[t] * CAP_ + pos[t]) * D_;
    float vals[3];
    float lsum = 0.f;
    #pragma unroll
    for (int i = 0; i < 3; i++) {
        int c = tid + i * 256;
        float v = att[(size_t)t * D_ + c] + yrow[c] * sc;
        vals[i] = v; lsum += v;
    }
    red[tid] = lsum; __syncthreads();
    for (int off = 128; off > 0; off >>= 1) { if (tid < off) red[tid] += red[tid + off]; __syncthreads(); }
    const float mu = red[0] * (1.0f / D_);
    __syncthreads();
    float lvar = 0.f;
    #pragma unroll
    for (int i = 0; i < 3; i++) { float d = vals[i] - mu; lvar += d * d; }
    red[tid] = lvar; __syncthreads();
    for (int off = 128; off > 0; off >>= 1) { if (tid < off) red[tid] += red[tid + off]; __syncthreads(); }
    const float rstd = rsqrtf(red[0] * (1.0f / D_) + 1e-12f);
    #pragma unroll
    for (int i = 0; i < 3; i++) {
        int c = tid + i * 256;
        out[(size_t)t * D_ + c] = (vals[i] - mu) * rstd * g[c] + bb[c];
    }
}

extern "C" void kernel_launch(void* const* d_in, const int* in_sizes, int n_in,
                              void* d_out, int out_size, void* d_ws, size_t ws_size,
                              hipStream_t stream) {
    const float* x     = (const float*)d_in[0];   // [B,S,D]
    const float* mask  = (const float*)d_in[1];   // [B,1,1,S]
    const float* Wq    = (const float*)d_in[2];
    const float* bq    = (const float*)d_in[3];
    const float* Wk    = (const float*)d_in[4];
    const float* bk    = (const float*)d_in[5];
    const float* Wv    = (const float*)d_in[6];
    const float* bv    = (const float*)d_in[7];
    const float* Wo    = (const float*)d_in[8];
    const float* bo    = (const float*)d_in[9];
    const float* ln1g  = (const float*)d_in[10];
    const float* ln1b  = (const float*)d_in[11];
    const float* Wr    = (const float*)d_in[12];
    const float* br    = (const float*)d_in[13];
    const float* W1    = (const float*)d_in[14];  // [E,D,FF]
    const float* b1    = (const float*)d_in[15];  // [E,FF]
    const float* W2    = (const float*)d_in[16];  // [E,FF,D]
    const float* b2    = (const float*)d_in[17];  // [E,D]
    const float* ln2g  = (const float*)d_in[18];
    const float* ln2b  = (const float*)d_in[19];
    float* out = (float*)d_out;

    float* ws = (float*)d_ws;
    const size_t TD = (size_t)T_ * D_;                 // 6291456
    float* q_buf   = ws;                               // [T,D]  (later reused by y)
    float* k_buf   = ws + TD;                          // [T,D]
    float* v_buf   = ws + 2 * TD;                      // [T,D]
    float* ctx_buf = ws + 3 * TD;                      // [T,D]
    float* att_buf = ws + 4 * TD;                      // [T,D]
    float* gate_b  = ws + 5 * TD;                      // [T]
    int*   eidx_b  = (int*)(ws + 5 * TD + T_);         // [T]
    int*   pos_b   = (int*)(ws + 5 * TD + 2 * T_);     // [T]
    float* scale_b = ws + 5 * TD + 3 * T_;             // [T]
    float* buf_b   = ws + 5 * TD + 4 * T_;             // [E,CAP,D] = 12582912
    float* h_buf   = buf_b + (size_t)E_ * CAP_ * D_;   // [CAP,FF] per-expert = 6291456
    float* proj_b  = q_buf;                            // reuse q region for ctx@Wo
    float* y_buf   = ws;                               // [E,CAP,D] reuses q+k regions

    dim3 blk(256);
    // QKV projections
    gemm_bias_kernel<<<dim3(D_ / BN, T_ / BM), blk, 0, stream>>>(x, Wq, bq, q_buf, T_, D_, D_, 0);
    gemm_bias_kernel<<<dim3(D_ / BN, T_ / BM), blk, 0, stream>>>(x, Wk, bk, k_buf, T_, D_, D_, 0);
    gemm_bias_kernel<<<dim3(D_ / BN, T_ / BM), blk, 0, stream>>>(x, Wv, bv, v_buf, T_, D_, D_, 0);
    // attention (flash-style tiles)
    flash_attn_kernel<<<dim3(S_ / 64, H_, B_), blk, 0, stream>>>(q_buf, k_buf, v_buf, mask, ctx_buf);
    // output projection (into q region; q is dead)
    gemm_bias_kernel<<<dim3(D_ / BN, T_ / BM), blk, 0, stream>>>(ctx_buf, Wo, bo, proj_b, T_, D_, D_, 0);
    // att_out = LN1(x + proj)
    add_ln_kernel<<<dim3(T_), blk, 0, stream>>>(x, proj_b, ln1g, ln1b, att_buf);
    // routing
    router_kernel<<<dim3(T_), dim3(64), 0, stream>>>(att_buf, Wr, br, gate_b, eidx_b);
    pos_scan_kernel<<<dim3(1), blk, 0, stream>>>(eidx_b, gate_b, pos_b, scale_b);
    // expert buffers
    hipMemsetAsync(buf_b, 0, (size_t)E_ * CAP_ * D_ * sizeof(float), stream);
    scatter_kernel<<<dim3(T_), blk, 0, stream>>>(att_buf, eidx_b, pos_b, scale_b, buf_b);
    // expert FFNs (h buffer reused per expert; y into q/k region which is dead)
    for (int e = 0; e < E_; e++) {
        const float* W1e = W1 + (size_t)e * D_ * FF_;
        const float* b1e = b1 + (size_t)e * FF_;
        const float* W2e = W2 + (size_t)e * FF_ * D_;
        const float* b2e = b2 + (size_t)e * D_;
        float* bufe = buf_b + (size_t)e * CAP_ * D_;
        float* ye   = y_buf + (size_t)e * CAP_ * D_;
        gemm_bias_kernel<<<dim3(FF_ / BN, CAP_ / BM), blk, 0, stream>>>(bufe, W1e, b1e, h_buf, CAP_, FF_, D_, 1);
        gemm_bias_kernel<<<dim3(D_ / BN, CAP_ / BM), blk, 0, stream>>>(h_buf, W2e, b2e, ye, CAP_, D_, FF_, 0);
    }
    // gather + residual + LN2
    final_ln_kernel<<<dim3(T_), blk, 0, stream>>>(att_buf, y_buf, eidx_b, pos_b, scale_b, ln2g, ln2b, out);
}

// Round 3
// 2120.889 us; speedup vs baseline: 5.6901x; 2.8845x over previous
//
#include <hip/hip_runtime.h>
#include <hip/hip_bf16.h>
#include <math.h>

#define B_ 8
#define S_ 1024
#define D_ 768
#define H_ 12
#define DH_ 64
#define FF_ 3072
#define E_ 8
#define CAP_ 2048
#define T_ (B_ * S_)

typedef __bf16 bf16_t;
typedef bf16_t bf16x8_t __attribute__((ext_vector_type(8)));
typedef bf16_t bf16x4_t __attribute__((ext_vector_type(4)));
typedef float floatx4_t __attribute__((ext_vector_type(4)));

// ---------------- generic tiled fp32 GEMM (attention path only)
#define BM 64
#define BN 64
#define BK 16

__global__ __launch_bounds__(256) void gemm_bias_kernel(
    const float* __restrict__ A, const float* __restrict__ W,
    const float* __restrict__ bias, float* __restrict__ C,
    int M, int N, int K, int apply_gelu)
{
    __shared__ float As[BK][BM + 1];
    __shared__ float Bs[BK][BN + 1];
    const int bx = blockIdx.x;
    const int by = blockIdx.y;
    const int tid = threadIdx.x;
    const int tx = tid & 15;
    const int ty = tid >> 4;
    const int row0 = by * BM, col0 = bx * BN;
    float acc[4][4] = {};
    for (int k0 = 0; k0 < K; k0 += BK) {
        #pragma unroll
        for (int i = 0; i < 4; i++) {
            int idx = tid + i * 256;
            int r = idx >> 4;
            int kk = idx & 15;
            As[kk][r] = A[(size_t)(row0 + r) * K + (k0 + kk)];
        }
        #pragma unroll
        for (int i = 0; i < 4; i++) {
            int idx = tid + i * 256;
            int kk = idx >> 6;
            int c = idx & 63;
            Bs[kk][c] = W[(size_t)(k0 + kk) * N + (col0 + c)];
        }
        __syncthreads();
        #pragma unroll
        for (int kk = 0; kk < BK; kk++) {
            float a[4], b[4];
            #pragma unroll
            for (int i = 0; i < 4; i++) a[i] = As[kk][ty * 4 + i];
            #pragma unroll
            for (int j = 0; j < 4; j++) b[j] = Bs[kk][tx * 4 + j];
            #pragma unroll
            for (int i = 0; i < 4; i++)
                #pragma unroll
                for (int j = 0; j < 4; j++) acc[i][j] += a[i] * b[j];
        }
        __syncthreads();
    }
    #pragma unroll
    for (int i = 0; i < 4; i++) {
        int r = row0 + ty * 4 + i;
        #pragma unroll
        for (int j = 0; j < 4; j++) {
            int c = col0 + tx * 4 + j;
            float v = acc[i][j] + bias[c];
            if (apply_gelu) v = 0.5f * v * (1.0f + erff(v * 0.70710678118654752f));
            C[(size_t)r * N + c] = v;
        }
    }
}

// ---------------- bf16 MFMA GEMM: C[M,N] = A[M,K] @ Bt[N,K]^T + bias (opt GELU), bf16 out
// z-batched; optional per-z row-count early exit. 128x128 tile, BK=32, 4 waves.
#define LSTR 40   // LDS row stride in bf16 elems (80 B = 5x16B -> 2-way-max bank aliasing)

__global__ __launch_bounds__(256) void mfma_gemm_kernel(
    const bf16_t* __restrict__ Abase, const bf16_t* __restrict__ Btbase,
    const float* __restrict__ biasbase, bf16_t* __restrict__ Cbase,
    const int* __restrict__ cnt, int cnt_off,
    int M, int N, int K,
    long strideAz, long strideBz, long strideBiasz, long strideCz,
    int apply_gelu)
{
    __shared__ bf16_t As[128 * LSTR];
    __shared__ bf16_t Bs[128 * LSTR];
    const int z = blockIdx.z;
    const int row0 = blockIdx.y * 128;
    const int col0 = blockIdx.x * 128;
    if (cnt && row0 >= cnt[cnt_off + z]) return;
    const bf16_t* A  = Abase + (size_t)z * strideAz;
    const bf16_t* Bt = Btbase + (size_t)z * strideBz;
    const float* bias = biasbase + (size_t)z * strideBiasz;
    bf16_t* C = Cbase + (size_t)z * strideCz;

    const int tid = threadIdx.x;
    const int lane = tid & 63, wave = tid >> 6;
    const int wm = (wave >> 1) * 64, wn = (wave & 1) * 64;
    const int l16 = lane & 15, quad = lane >> 4;

    floatx4_t acc[4][4] = {};

    const int ch0 = tid, ch1 = tid + 256;   // 16B-chunk ids (512 chunks per tile)
    const int r0a = ch0 >> 2, kc0 = (ch0 & 3) * 8;
    const int r1a = ch1 >> 2, kc1 = (ch1 & 3) * 8;

    for (int k0 = 0; k0 < K; k0 += 32) {
        __syncthreads();
        *(int4*)&As[r0a * LSTR + kc0] = *(const int4*)&A[(size_t)(row0 + r0a) * K + k0 + kc0];
        *(int4*)&As[r1a * LSTR + kc1] = *(const int4*)&A[(size_t)(row0 + r1a) * K + k0 + kc1];
        *(int4*)&Bs[r0a * LSTR + kc0] = *(const int4*)&Bt[(size_t)(col0 + r0a) * K + k0 + kc0];
        *(int4*)&Bs[r1a * LSTR + kc1] = *(const int4*)&Bt[(size_t)(col0 + r1a) * K + k0 + kc1];
        __syncthreads();
        bf16x8_t a[4], b[4];
        #pragma unroll
        for (int mt = 0; mt < 4; mt++)
            a[mt] = *(bf16x8_t*)&As[(wm + mt * 16 + l16) * LSTR + quad * 8];
        #pragma unroll
        for (int nt = 0; nt < 4; nt++)
            b[nt] = *(bf16x8_t*)&Bs[(wn + nt * 16 + l16) * LSTR + quad * 8];
        #pragma unroll
        for (int mt = 0; mt < 4; mt++)
            #pragma unroll
            for (int nt = 0; nt < 4; nt++)
                acc[mt][nt] = __builtin_amdgcn_mfma_f32_16x16x32_bf16(a[mt], b[nt], acc[mt][nt], 0, 0, 0);
    }

    #pragma unroll
    for (int mt = 0; mt < 4; mt++) {
        #pragma unroll
        for (int nt = 0; nt < 4; nt++) {
            const int col = col0 + wn + nt * 16 + l16;
            const float bv = bias[col];
            #pragma unroll
            for (int r = 0; r < 4; r++) {
                const int row = row0 + wm + mt * 16 + quad * 4 + r;
                float v = acc[mt][nt][r] + bv;
                if (apply_gelu) v = 0.5f * v * (1.0f + erff(v * 0.70710678118654752f));
                C[(size_t)row * N + col] = (bf16_t)v;
            }
        }
    }
}

// ---------------- transpose + cast: fp32 src[R,C] -> bf16 dst[C,R], z-batched
__global__ __launch_bounds__(256) void transpose_cast_kernel(
    const float* __restrict__ src, bf16_t* __restrict__ dst, int R, int C)
{
    __shared__ float tile[32][33];
    const size_t zoff = (size_t)blockIdx.z * R * C;
    const float* s = src + zoff;
    bf16_t* d = dst + zoff;
    const int r0 = blockIdx.y * 32, c0 = blockIdx.x * 32;
    const int tid = threadIdx.x;
    const int tr = tid >> 3, tc4 = (tid & 7) * 4;
    float4 v = *(const float4*)&s[(size_t)(r0 + tr) * C + c0 + tc4];
    tile[tr][tc4 + 0] = v.x; tile[tr][tc4 + 1] = v.y;
    tile[tr][tc4 + 2] = v.z; tile[tr][tc4 + 3] = v.w;
    __syncthreads();
    const int cc = tid >> 3, rr4 = (tid & 7) * 4;
    bf16x4_t o;
    #pragma unroll
    for (int i = 0; i < 4; i++) o[i] = (bf16_t)tile[rr4 + i][cc];
    *(bf16x4_t*)&d[(size_t)(c0 + cc) * R + r0 + rr4] = o;
}

// ---------------- flash-style attention (unchanged fp32)
#define AS 68

__global__ __launch_bounds__(256) void flash_attn_kernel(
    const float* __restrict__ q, const float* __restrict__ k,
    const float* __restrict__ v, const float* __restrict__ mask,
    float* __restrict__ ctx)
{
    __shared__ float Qs[64 * AS];
    __shared__ float Ks[64 * AS];
    __shared__ float VsT[64 * AS];
    __shared__ float Ps[64 * AS];
    const int qt = blockIdx.x, h = blockIdx.y, b = blockIdx.z;
    const int tid = threadIdx.x;
    const int tx = tid & 15, ty = tid >> 4;
    const int q0 = qt * 64;
    const size_t headbase = (size_t)b * S_ * D_ + (size_t)h * DH_;

    #pragma unroll
    for (int i = 0; i < 4; i++) {
        int idx = i * 256 + tid;
        int r = idx >> 4, fc = idx & 15;
        *(float4*)&Qs[r * AS + fc * 4] =
            *(const float4*)&q[headbase + (size_t)(q0 + r) * D_ + fc * 4];
    }

    float O[4][4] = {};
    float mrun[4], lrun[4];
    #pragma unroll
    for (int i = 0; i < 4; i++) { mrun[i] = -1e30f; lrun[i] = 0.f; }

    for (int kt = 0; kt < S_ / 64; kt++) {
        const int k0 = kt * 64;
        __syncthreads();
        #pragma unroll
        for (int i = 0; i < 4; i++) {
            int idx = i * 256 + tid;
            int r = idx >> 4, fc = idx & 15;
            *(float4*)&Ks[r * AS + fc * 4] =
                *(const float4*)&k[headbase + (size_t)(k0 + r) * D_ + fc * 4];
        }
        #pragma unroll
        for (int i = 0; i < 16; i++) {
            int idx = i * 256 + tid;
            int key = idx >> 6, d = idx & 63;
            VsT[d * AS + key] = v[headbase + (size_t)(k0 + key) * D_ + d];
        }
        __syncthreads();

        float acc[4][4] = {};
        #pragma unroll 4
        for (int d0 = 0; d0 < DH_; d0 += 4) {
            float4 a4[4], b4[4];
            #pragma unroll
            for (int i = 0; i < 4; i++) a4[i] = *(float4*)&Qs[(ty * 4 + i) * AS + d0];
            #pragma unroll
            for (int j = 0; j < 4; j++) b4[j] = *(float4*)&Ks[(tx + 16 * j) * AS + d0];
            #pragma unroll
            for (int i = 0; i < 4; i++)
                #pragma unroll
                for (int j = 0; j < 4; j++)
                    acc[i][j] += a4[i].x * b4[j].x + a4[i].y * b4[j].y
                               + a4[i].z * b4[j].z + a4[i].w * b4[j].w;
        }
        float mk[4];
        #pragma unroll
        for (int j = 0; j < 4; j++) mk[j] = mask[b * S_ + k0 + tx + 16 * j];

        #pragma unroll
        for (int i = 0; i < 4; i++) {
            float s[4];
            float rmax = -1e30f;
            #pragma unroll
            for (int j = 0; j < 4; j++) {
                s[j] = acc[i][j] * 0.125f + mk[j];
                rmax = fmaxf(rmax, s[j]);
            }
            #pragma unroll
            for (int off = 1; off < 16; off <<= 1) rmax = fmaxf(rmax, __shfl_xor(rmax, off));
            const float mnew = fmaxf(mrun[i], rmax);
            const float alpha = __expf(mrun[i] - mnew);
            float rsum = 0.f;
            #pragma unroll
            for (int j = 0; j < 4; j++) {
                float p = __expf(s[j] - mnew);
                Ps[(ty * 4 + i) * AS + tx + 16 * j] = p;
                rsum += p;
            }
            #pragma unroll
            for (int off = 1; off < 16; off <<= 1) rsum += __shfl_xor(rsum, off);
            lrun[i] = lrun[i] * alpha + rsum;
            mrun[i] = mnew;
            #pragma unroll
            for (int j = 0; j < 4; j++) O[i][j] *= alpha;
        }
        __syncthreads();

        #pragma unroll 4
        for (int c0 = 0; c0 < 64; c0 += 4) {
            float4 a4[4], b4[4];
            #pragma unroll
            for (int i = 0; i < 4; i++) a4[i] = *(float4*)&Ps[(ty * 4 + i) * AS + c0];
            #pragma unroll
            for (int j = 0; j < 4; j++) b4[j] = *(float4*)&VsT[(tx + 16 * j) * AS + c0];
            #pragma unroll
            for (int i = 0; i < 4; i++)
                #pragma unroll
                for (int j = 0; j < 4; j++)
                    O[i][j] += a4[i].x * b4[j].x + a4[i].y * b4[j].y
                             + a4[i].z * b4[j].z + a4[i].w * b4[j].w;
        }
    }

    #pragma unroll
    for (int i = 0; i < 4; i++) {
        const float invl = 1.0f / lrun[i];
        #pragma unroll
        for (int j = 0; j < 4; j++)
            ctx[headbase + (size_t)(q0 + ty * 4 + i) * D_ + tx + 16 * j] = O[i][j] * invl;
    }
}

// ---------------- out[t] = LN(x[t] + y[t]) * g + b
__global__ __launch_bounds__(256) void add_ln_kernel(
    const float* __restrict__ x, const float* __restrict__ y,
    const float* __restrict__ g, const float* __restrict__ bb,
    float* __restrict__ out)
{
    const int t = blockIdx.x;
    const int tid = threadIdx.x;
    __shared__ float red[256];
    float vals[3];
    float lsum = 0.f;
    #pragma unroll
    for (int i = 0; i < 3; i++) {
        int c = tid + i * 256;
        float v = x[(size_t)t * D_ + c] + y[(size_t)t * D_ + c];
        vals[i] = v; lsum += v;
    }
    red[tid] = lsum; __syncthreads();
    for (int off = 128; off > 0; off >>= 1) { if (tid < off) red[tid] += red[tid + off]; __syncthreads(); }
    const float mu = red[0] * (1.0f / D_);
    __syncthreads();
    float lvar = 0.f;
    #pragma unroll
    for (int i = 0; i < 3; i++) { float d = vals[i] - mu; lvar += d * d; }
    red[tid] = lvar; __syncthreads();
    for (int off = 128; off > 0; off >>= 1) { if (tid < off) red[tid] += red[tid + off]; __syncthreads(); }
    const float rstd = rsqrtf(red[0] * (1.0f / D_) + 1e-12f);
    #pragma unroll
    for (int i = 0; i < 3; i++) {
        int c = tid + i * 256;
        out[(size_t)t * D_ + c] = (vals[i] - mu) * rstd * g[c] + bb[c];
    }
}

// ---------------- router: 1 wave per token
__global__ __launch_bounds__(64) void router_kernel(
    const float* __restrict__ att, const float* __restrict__ Wr,
    const float* __restrict__ br, float* __restrict__ gate, int* __restrict__ eidx)
{
    const int t = blockIdx.x;
    const int lane = threadIdx.x;
    float lg[E_] = {};
    for (int d = lane; d < D_; d += 64) {
        float xv = att[(size_t)t * D_ + d];
        #pragma unroll
        for (int e = 0; e < E_; e++) lg[e] += xv * Wr[d * E_ + e];
    }
    #pragma unroll
    for (int off = 32; off > 0; off >>= 1)
        #pragma unroll
        for (int e = 0; e < E_; e++) lg[e] += __shfl_down(lg[e], off);
    if (lane == 0) {
        float mx = -1e30f; int mi = 0;
        #pragma unroll
        for (int e = 0; e < E_; e++) {
            lg[e] += br[e];
            if (lg[e] > mx) { mx = lg[e]; mi = e; }
        }
        float ssum = 0.f;
        #pragma unroll
        for (int e = 0; e < E_; e++) ssum += expf(lg[e] - mx);
        gate[t] = 1.0f / ssum;
        eidx[t] = mi;
    }
}

// ---------------- position-within-expert scan (single block) + per-expert counts
__global__ __launch_bounds__(256) void pos_scan_kernel(
    const int* __restrict__ eidx, const float* __restrict__ gate,
    int* __restrict__ pos, float* __restrict__ scale, int* __restrict__ cnt_out)
{
    __shared__ int cnt[256][E_];
    const int tid = threadIdx.x;
    const int start = tid * (T_ / 256);
    int lc[E_] = {};
    for (int i = 0; i < T_ / 256; i++) lc[eidx[start + i]]++;
    #pragma unroll
    for (int e = 0; e < E_; e++) cnt[tid][e] = lc[e];
    __syncthreads();
    if (tid < E_) {
        int run = 0;
        for (int i = 0; i < 256; i++) { int c = cnt[i][tid]; cnt[i][tid] = run; run += c; }
        cnt_out[tid] = run;
    }
    __syncthreads();
    int off[E_];
    #pragma unroll
    for (int e = 0; e < E_; e++) off[e] = cnt[tid][e];
    for (int i = 0; i < T_ / 256; i++) {
        int tk = start + i;
        int e = eidx[tk];
        int p = off[e]++;
        bool keep = p < CAP_;
        pos[tk] = p < CAP_ - 1 ? p : CAP_ - 1;
        scale[tk] = keep ? gate[tk] : 0.0f;
    }
}

// ---------------- scatter kept tokens into per-expert bf16 buffers
__global__ __launch_bounds__(256) void scatter_kernel(
    const float* __restrict__ att, const int* __restrict__ eidx,
    const int* __restrict__ pos, const float* __restrict__ scale,
    bf16_t* __restrict__ buf)
{
    const int t = blockIdx.x;
    if (scale[t] == 0.0f) return;
    const int tid = threadIdx.x;
    const float* src = att + (size_t)t * D_;
    bf16_t* dst = buf + ((size_t)eidx[t] * CAP_ + pos[t]) * D_;
    for (int i = tid; i < D_; i += 256) dst[i] = (bf16_t)src[i];
}

// ---------------- gather (bf16 y) + residual + final LN
__global__ __launch_bounds__(256) void final_ln_kernel(
    const float* __restrict__ att, const bf16_t* __restrict__ y,
    const int* __restrict__ eidx, const int* __restrict__ pos,
    const float* __restrict__ scale,
    const float* __restrict__ g, const float* __restrict__ bb,
    float* __restrict__ out)
{
    const int t = blockIdx.x;
    const int tid = threadIdx.x;
    __shared__ float red[256];
    const float sc = scale[t];
    const bf16_t* yrow = y + ((size_t)eidx[t] * CAP_ + pos[t]) * D_;
    float vals[3];
    float lsum = 0.f;
    #pragma unroll
    for (int i = 0; i < 3; i++) {
        int c = tid + i * 256;
        float v = att[(size_t)t * D_ + c] + (float)yrow[c] * sc;
        vals[i] = v; lsum += v;
    }
    red[tid] = lsum; __syncthreads();
    for (int off = 128; off > 0; off >>= 1) { if (tid < off) red[tid] += red[tid + off]; __syncthreads(); }
    const float mu = red[0] * (1.0f / D_);
    __syncthreads();
    float lvar = 0.f;
    #pragma unroll
    for (int i = 0; i < 3; i++) { float d = vals[i] - mu; lvar += d * d; }
    red[tid] = lvar; __syncthreads();
    for (int off = 128; off > 0; off >>= 1) { if (tid < off) red[tid] += red[tid + off]; __syncthreads(); }
    const float rstd = rsqrtf(red[0] * (1.0f / D_) + 1e-12f);
    #pragma unroll
    for (int i = 0; i < 3; i++) {
        int c = tid + i * 256;
        out[(size_t)t * D_ + c] = (vals[i] - mu) * rstd * g[c] + bb[c];
    }
}

extern "C" void kernel_launch(void* const* d_in, const int* in_sizes, int n_in,
                              void* d_out, int out_size, void* d_ws, size_t ws_size,
                              hipStream_t stream) {
    const float* x     = (const float*)d_in[0];
    const float* mask  = (const float*)d_in[1];
    const float* Wq    = (const float*)d_in[2];
    const float* bq    = (const float*)d_in[3];
    const float* Wk    = (const float*)d_in[4];
    const float* bk    = (const float*)d_in[5];
    const float* Wv    = (const float*)d_in[6];
    const float* bv    = (const float*)d_in[7];
    const float* Wo    = (const float*)d_in[8];
    const float* bo    = (const float*)d_in[9];
    const float* ln1g  = (const float*)d_in[10];
    const float* ln1b  = (const float*)d_in[11];
    const float* Wr    = (const float*)d_in[12];
    const float* br    = (const float*)d_in[13];
    const float* W1    = (const float*)d_in[14];
    const float* b1    = (const float*)d_in[15];
    const float* W2    = (const float*)d_in[16];
    const float* b2    = (const float*)d_in[17];
    const float* ln2g  = (const float*)d_in[18];
    const float* ln2b  = (const float*)d_in[19];
    float* out = (float*)d_out;

    char* ws = (char*)d_ws;
    const size_t TDB = (size_t)T_ * D_ * 4;            // 25,165,824 B
    float* q_buf   = (float*)(ws);                     // [T,D] fp32; later proj; later W1T/W2T/h overlay
    float* k_buf   = (float*)(ws + TDB);
    float* v_buf   = (float*)(ws + 2 * TDB);
    float* ctx_buf = (float*)(ws + 3 * TDB);
    float* att_buf = (float*)(ws + 4 * TDB);
    char*  smallp  = ws + 5 * TDB;
    float* gate_b  = (float*)(smallp);
    int*   eidx_b  = (int*)(smallp + 32768);
    int*   pos_b   = (int*)(smallp + 2 * 32768);
    float* scale_b = (float*)(smallp + 3 * 32768);
    int*   cnt_b   = (int*)(smallp + 4 * 32768);
    bf16_t* buf_b  = (bf16_t*)(smallp + 4 * 32768 + 128);                 // [E,CAP,D] bf16
    bf16_t* y_b    = (bf16_t*)((char*)buf_b + (size_t)E_ * CAP_ * D_ * 2); // [E,CAP,D] bf16
    // overlays of the q..ctx block (valid after add_ln):
    bf16_t* W1T = (bf16_t*)(ws);                                   // [E][FF,D] bf16 = 37.7 MB
    bf16_t* W2T = (bf16_t*)(ws + (size_t)E_ * FF_ * D_ * 2);       // [E][D,FF] bf16 = 37.7 MB
    bf16_t* h_b = (bf16_t*)(ws + (size_t)2 * E_ * FF_ * D_ * 2);   // [2,CAP,FF] bf16 = 25.2 MB
    float* proj_b = q_buf;

    dim3 blk(256);
    // ---- attention path (fp32, unchanged semantics: feeds the router, must stay accurate)
    gemm_bias_kernel<<<dim3(D_ / BN, T_ / BM), blk, 0, stream>>>(x, Wq, bq, q_buf, T_, D_, D_, 0);
    gemm_bias_kernel<<<dim3(D_ / BN, T_ / BM), blk, 0, stream>>>(x, Wk, bk, k_buf, T_, D_, D_, 0);
    gemm_bias_kernel<<<dim3(D_ / BN, T_ / BM), blk, 0, stream>>>(x, Wv, bv, v_buf, T_, D_, D_, 0);
    flash_attn_kernel<<<dim3(S_ / 64, H_, B_), blk, 0, stream>>>(q_buf, k_buf, v_buf, mask, ctx_buf);
    gemm_bias_kernel<<<dim3(D_ / BN, T_ / BM), blk, 0, stream>>>(ctx_buf, Wo, bo, proj_b, T_, D_, D_, 0);
    add_ln_kernel<<<dim3(T_), blk, 0, stream>>>(x, proj_b, ln1g, ln1b, att_buf);
    // ---- routing (fp32)
    router_kernel<<<dim3(T_), dim3(64), 0, stream>>>(att_buf, Wr, br, gate_b, eidx_b);
    pos_scan_kernel<<<dim3(1), blk, 0, stream>>>(eidx_b, gate_b, pos_b, scale_b, cnt_b);
    // ---- weight transpose-casts into dead q..ctx region (safe after add_ln)
    transpose_cast_kernel<<<dim3(FF_ / 32, D_ / 32, E_), blk, 0, stream>>>(W1, W1T, D_, FF_);
    transpose_cast_kernel<<<dim3(D_ / 32, FF_ / 32, E_), blk, 0, stream>>>(W2, W2T, FF_, D_);
    // ---- expert buffers
    hipMemsetAsync(buf_b, 0, (size_t)E_ * CAP_ * D_ * 2, stream);
    scatter_kernel<<<dim3(T_), blk, 0, stream>>>(att_buf, eidx_b, pos_b, scale_b, buf_b);
    // ---- expert FFNs, bf16 MFMA, 2 experts per z-batch (h buffer reused)
    for (int bch = 0; bch < 4; bch++) {
        const int e0 = bch * 2;
        mfma_gemm_kernel<<<dim3(FF_ / 128, CAP_ / 128, 2), blk, 0, stream>>>(
            buf_b + (size_t)e0 * CAP_ * D_, W1T + (size_t)e0 * FF_ * D_,
            b1 + (size_t)e0 * FF_, h_b,
            cnt_b, e0, CAP_, FF_, D_,
            (long)CAP_ * D_, (long)FF_ * D_, (long)FF_, (long)CAP_ * FF_, 1);
        mfma_gemm_kernel<<<dim3(D_ / 128, CAP_ / 128, 2), blk, 0, stream>>>(
            h_b, W2T + (size_t)e0 * D_ * FF_,
            b2 + (size_t)e0 * D_, y_b + (size_t)e0 * CAP_ * D_,
            cnt_b, e0, CAP_, D_, FF_,
            (long)CAP_ * FF_, (long)D_ * FF_, (long)D_, (long)CAP_ * D_, 0);
    }
    // ---- gather + residual + LN2
    final_ln_kernel<<<dim3(T_), blk, 0, stream>>>(att_buf, y_b, eidx_b, pos_b, scale_b, ln2g, ln2b, out);
}

// Round 4
// 1801.907 us; speedup vs baseline: 6.6974x; 1.1770x over previous
//
#include <hip/hip_runtime.h>
#include <hip/hip_bf16.h>
#include <math.h>

#define B_ 8
#define S_ 1024
#define D_ 768
#define H_ 12
#define DH_ 64
#define FF_ 3072
#define E_ 8
#define CAP_ 2048
#define T_ (B_ * S_)

typedef __bf16 bf16_t;
typedef bf16_t bf16x8_t __attribute__((ext_vector_type(8)));
typedef bf16_t bf16x4_t __attribute__((ext_vector_type(4)));
typedef float floatx4_t __attribute__((ext_vector_type(4)));

// ---------------- fp32 GEMM, 128x128 tile, 8x8 microtile (4+4 split): C = A@W + bias
#define GBK 16
#define GAS 132   // LDS row stride (floats)

__global__ __launch_bounds__(256) void gemm_f32_kernel(
    const float* __restrict__ A, const float* __restrict__ W,
    const float* __restrict__ bias, float* __restrict__ C,
    int M, int N, int K)
{
    __shared__ float As[GBK][GAS];   // transposed: As[k][m]
    __shared__ float Bs[GBK][GAS];   // Bs[k][n]
    const int row0 = blockIdx.y * 128, col0 = blockIdx.x * 128;
    const int tid = threadIdx.x;
    const int tx = tid & 15, ty = tid >> 4;          // 16x16 threads
    float acc[2][4][2][4] = {};                       // [mhalf][i][nhalf][j]
    const int ar = tid >> 2;                          // 0..63
    const int akc = (tid & 3) * 4;                    // 0,4,8,12
    const int bk = tid >> 5;                          // 0..7
    const int bc = (tid & 31) * 4;                    // 0..124

    for (int k0 = 0; k0 < K; k0 += GBK) {
        __syncthreads();
        #pragma unroll
        for (int g = 0; g < 2; g++) {
            const int r = ar + g * 64;
            float4 va = *(const float4*)&A[(size_t)(row0 + r) * K + k0 + akc];
            As[akc + 0][r] = va.x; As[akc + 1][r] = va.y;
            As[akc + 2][r] = va.z; As[akc + 3][r] = va.w;
        }
        #pragma unroll
        for (int g = 0; g < 2; g++) {
            const int kk = bk + g * 8;
            *(float4*)&Bs[kk][bc] = *(const float4*)&W[(size_t)(k0 + kk) * N + col0 + bc];
        }
        __syncthreads();
        #pragma unroll
        for (int kk = 0; kk < GBK; kk++) {
            float4 a0 = *(float4*)&As[kk][ty * 4];
            float4 a1 = *(float4*)&As[kk][64 + ty * 4];
            float4 b0 = *(float4*)&Bs[kk][tx * 4];
            float4 b1 = *(float4*)&Bs[kk][64 + tx * 4];
            const float am[2][4] = {{a0.x, a0.y, a0.z, a0.w}, {a1.x, a1.y, a1.z, a1.w}};
            const float bn[2][4] = {{b0.x, b0.y, b0.z, b0.w}, {b1.x, b1.y, b1.z, b1.w}};
            #pragma unroll
            for (int mh = 0; mh < 2; mh++)
                #pragma unroll
                for (int i = 0; i < 4; i++)
                    #pragma unroll
                    for (int nh = 0; nh < 2; nh++)
                        #pragma unroll
                        for (int j = 0; j < 4; j++)
                            acc[mh][i][nh][j] += am[mh][i] * bn[nh][j];
        }
    }
    #pragma unroll
    for (int mh = 0; mh < 2; mh++) {
        #pragma unroll
        for (int i = 0; i < 4; i++) {
            const int row = row0 + mh * 64 + ty * 4 + i;
            #pragma unroll
            for (int nh = 0; nh < 2; nh++) {
                const int col = col0 + nh * 64 + tx * 4;
                float4 o;
                o.x = acc[mh][i][nh][0] + bias[col + 0];
                o.y = acc[mh][i][nh][1] + bias[col + 1];
                o.z = acc[mh][i][nh][2] + bias[col + 2];
                o.w = acc[mh][i][nh][3] + bias[col + 3];
                *(float4*)&C[(size_t)row * N + col] = o;
            }
        }
    }
}

// ---------------- bf16 MFMA GEMM: C[M,N] = A[M,K] @ Bt[N,K]^T + bias (opt GELU), bf16 out
#define LSTR 40

__global__ __launch_bounds__(256) void mfma_gemm_kernel(
    const bf16_t* __restrict__ Abase, const bf16_t* __restrict__ Btbase,
    const float* __restrict__ biasbase, bf16_t* __restrict__ Cbase,
    const int* __restrict__ cnt, int cnt_off,
    int M, int N, int K,
    long strideAz, long strideBz, long strideBiasz, long strideCz,
    int apply_gelu)
{
    __shared__ bf16_t As[128 * LSTR];
    __shared__ bf16_t Bs[128 * LSTR];
    const int z = blockIdx.z;
    const int row0 = blockIdx.y * 128;
    const int col0 = blockIdx.x * 128;
    if (cnt && row0 >= cnt[cnt_off + z]) return;
    const bf16_t* A  = Abase + (size_t)z * strideAz;
    const bf16_t* Bt = Btbase + (size_t)z * strideBz;
    const float* bias = biasbase + (size_t)z * strideBiasz;
    bf16_t* C = Cbase + (size_t)z * strideCz;

    const int tid = threadIdx.x;
    const int lane = tid & 63, wave = tid >> 6;
    const int wm = (wave >> 1) * 64, wn = (wave & 1) * 64;
    const int l16 = lane & 15, quad = lane >> 4;

    floatx4_t acc[4][4] = {};

    const int ch0 = tid, ch1 = tid + 256;
    const int r0a = ch0 >> 2, kc0 = (ch0 & 3) * 8;
    const int r1a = ch1 >> 2, kc1 = (ch1 & 3) * 8;

    for (int k0 = 0; k0 < K; k0 += 32) {
        __syncthreads();
        *(int4*)&As[r0a * LSTR + kc0] = *(const int4*)&A[(size_t)(row0 + r0a) * K + k0 + kc0];
        *(int4*)&As[r1a * LSTR + kc1] = *(const int4*)&A[(size_t)(row0 + r1a) * K + k0 + kc1];
        *(int4*)&Bs[r0a * LSTR + kc0] = *(const int4*)&Bt[(size_t)(col0 + r0a) * K + k0 + kc0];
        *(int4*)&Bs[r1a * LSTR + kc1] = *(const int4*)&Bt[(size_t)(col0 + r1a) * K + k0 + kc1];
        __syncthreads();
        bf16x8_t a[4], b[4];
        #pragma unroll
        for (int mt = 0; mt < 4; mt++)
            a[mt] = *(bf16x8_t*)&As[(wm + mt * 16 + l16) * LSTR + quad * 8];
        #pragma unroll
        for (int nt = 0; nt < 4; nt++)
            b[nt] = *(bf16x8_t*)&Bs[(wn + nt * 16 + l16) * LSTR + quad * 8];
        #pragma unroll
        for (int mt = 0; mt < 4; mt++)
            #pragma unroll
            for (int nt = 0; nt < 4; nt++)
                acc[mt][nt] = __builtin_amdgcn_mfma_f32_16x16x32_bf16(a[mt], b[nt], acc[mt][nt], 0, 0, 0);
    }

    #pragma unroll
    for (int mt = 0; mt < 4; mt++) {
        #pragma unroll
        for (int nt = 0; nt < 4; nt++) {
            const int col = col0 + wn + nt * 16 + l16;
            const float bv = bias[col];
            #pragma unroll
            for (int r = 0; r < 4; r++) {
                const int row = row0 + wm + mt * 16 + quad * 4 + r;
                float v = acc[mt][nt][r] + bv;
                if (apply_gelu) v = 0.5f * v * (1.0f + erff(v * 0.70710678118654752f));
                C[(size_t)row * N + col] = (bf16_t)v;
            }
        }
    }
}

// ---------------- transpose + cast: fp32 src[R,C] -> bf16 dst[C,R], z-batched
__global__ __launch_bounds__(256) void transpose_cast_kernel(
    const float* __restrict__ src, bf16_t* __restrict__ dst, int R, int C)
{
    __shared__ float tile[32][33];
    const size_t zoff = (size_t)blockIdx.z * R * C;
    const float* s = src + zoff;
    bf16_t* d = dst + zoff;
    const int r0 = blockIdx.y * 32, c0 = blockIdx.x * 32;
    const int tid = threadIdx.x;
    const int tr = tid >> 3, tc4 = (tid & 7) * 4;
    float4 v = *(const float4*)&s[(size_t)(r0 + tr) * C + c0 + tc4];
    tile[tr][tc4 + 0] = v.x; tile[tr][tc4 + 1] = v.y;
    tile[tr][tc4 + 2] = v.z; tile[tr][tc4 + 3] = v.w;
    __syncthreads();
    const int cc = tid >> 3, rr4 = (tid & 7) * 4;
    bf16x4_t o;
    #pragma unroll
    for (int i = 0; i < 4; i++) o[i] = (bf16_t)tile[rr4 + i][cc];
    *(bf16x4_t*)&d[(size_t)(c0 + cc) * R + r0 + rr4] = o;
}

// ---------------- flash-style attention; P reuses Ks LDS region (3 blocks/CU)
#define AS 68

__global__ __launch_bounds__(256) void flash_attn_kernel(
    const float* __restrict__ q, const float* __restrict__ k,
    const float* __restrict__ v, const float* __restrict__ mask,
    float* __restrict__ ctx)
{
    __shared__ float Qs[64 * AS];
    __shared__ float Ks[64 * AS];    // holds K tile, then reused for P
    __shared__ float VsT[64 * AS];
    const int qt = blockIdx.x, h = blockIdx.y, b = blockIdx.z;
    const int tid = threadIdx.x;
    const int tx = tid & 15, ty = tid >> 4;
    const int q0 = qt * 64;
    const size_t headbase = (size_t)b * S_ * D_ + (size_t)h * DH_;

    #pragma unroll
    for (int i = 0; i < 4; i++) {
        int idx = i * 256 + tid;
        int r = idx >> 4, fc = idx & 15;
        *(float4*)&Qs[r * AS + fc * 4] =
            *(const float4*)&q[headbase + (size_t)(q0 + r) * D_ + fc * 4];
    }

    float O[4][4] = {};
    float mrun[4], lrun[4];
    #pragma unroll
    for (int i = 0; i < 4; i++) { mrun[i] = -1e30f; lrun[i] = 0.f; }

    for (int kt = 0; kt < S_ / 64; kt++) {
        const int k0 = kt * 64;
        __syncthreads();   // prev iter's P/V readers done
        #pragma unroll
        for (int i = 0; i < 4; i++) {
            int idx = i * 256 + tid;
            int r = idx >> 4, fc = idx & 15;
            *(float4*)&Ks[r * AS + fc * 4] =
                *(const float4*)&k[headbase + (size_t)(k0 + r) * D_ + fc * 4];
        }
        #pragma unroll
        for (int i = 0; i < 16; i++) {
            int idx = i * 256 + tid;
            int key = idx >> 6, d = idx & 63;
            VsT[d * AS + key] = v[headbase + (size_t)(k0 + key) * D_ + d];
        }
        __syncthreads();

        // S = Q @ K^T
        float acc[4][4] = {};
        #pragma unroll 4
        for (int d0 = 0; d0 < DH_; d0 += 4) {
            float4 a4[4], b4[4];
            #pragma unroll
            for (int i = 0; i < 4; i++) a4[i] = *(float4*)&Qs[(ty * 4 + i) * AS + d0];
            #pragma unroll
            for (int j = 0; j < 4; j++) b4[j] = *(float4*)&Ks[(tx + 16 * j) * AS + d0];
            #pragma unroll
            for (int i = 0; i < 4; i++)
                #pragma unroll
                for (int j = 0; j < 4; j++)
                    acc[i][j] += a4[i].x * b4[j].x + a4[i].y * b4[j].y
                               + a4[i].z * b4[j].z + a4[i].w * b4[j].w;
        }
        float mk[4];
        #pragma unroll
        for (int j = 0; j < 4; j++) mk[j] = mask[b * S_ + k0 + tx + 16 * j];

        __syncthreads();   // all QK reads of Ks done before P overwrites it

        // online softmax; write P into Ks region
        #pragma unroll
        for (int i = 0; i < 4; i++) {
            float s[4];
            float rmax = -1e30f;
            #pragma unroll
            for (int j = 0; j < 4; j++) {
                s[j] = acc[i][j] * 0.125f + mk[j];
                rmax = fmaxf(rmax, s[j]);
            }
            #pragma unroll
            for (int off = 1; off < 16; off <<= 1) rmax = fmaxf(rmax, __shfl_xor(rmax, off));
            const float mnew = fmaxf(mrun[i], rmax);
            const float alpha = __expf(mrun[i] - mnew);
            float rsum = 0.f;
            #pragma unroll
            for (int j = 0; j < 4; j++) {
                float p = __expf(s[j] - mnew);
                Ks[(ty * 4 + i) * AS + tx + 16 * j] = p;
                rsum += p;
            }
            #pragma unroll
            for (int off = 1; off < 16; off <<= 1) rsum += __shfl_xor(rsum, off);
            lrun[i] = lrun[i] * alpha + rsum;
            mrun[i] = mnew;
            #pragma unroll
            for (int j = 0; j < 4; j++) O[i][j] *= alpha;
        }
        __syncthreads();   // P visible to all

        // O += P @ V
        #pragma unroll 4
        for (int c0 = 0; c0 < 64; c0 += 4) {
            float4 a4[4], b4[4];
            #pragma unroll
            for (int i = 0; i < 4; i++) a4[i] = *(float4*)&Ks[(ty * 4 + i) * AS + c0];
            #pragma unroll
            for (int j = 0; j < 4; j++) b4[j] = *(float4*)&VsT[(tx + 16 * j) * AS + c0];
            #pragma unroll
            for (int i = 0; i < 4; i++)
                #pragma unroll
                for (int j = 0; j < 4; j++)
                    O[i][j] += a4[i].x * b4[j].x + a4[i].y * b4[j].y
                             + a4[i].z * b4[j].z + a4[i].w * b4[j].w;
        }
    }

    #pragma unroll
    for (int i = 0; i < 4; i++) {
        const float invl = 1.0f / lrun[i];
        #pragma unroll
        for (int j = 0; j < 4; j++)
            ctx[headbase + (size_t)(q0 + ty * 4 + i) * D_ + tx + 16 * j] = O[i][j] * invl;
    }
}

// ---------------- out[t] = LN(x[t] + y[t]) * g + b
__global__ __launch_bounds__(256) void add_ln_kernel(
    const float* __restrict__ x, const float* __restrict__ y,
    const float* __restrict__ g, const float* __restrict__ bb,
    float* __restrict__ out)
{
    const int t = blockIdx.x;
    const int tid = threadIdx.x;
    __shared__ float red[256];
    float vals[3];
    float lsum = 0.f;
    #pragma unroll
    for (int i = 0; i < 3; i++) {
        int c = tid + i * 256;
        float v = x[(size_t)t * D_ + c] + y[(size_t)t * D_ + c];
        vals[i] = v; lsum += v;
    }
    red[tid] = lsum; __syncthreads();
    for (int off = 128; off > 0; off >>= 1) { if (tid < off) red[tid] += red[tid + off]; __syncthreads(); }
    const float mu = red[0] * (1.0f / D_);
    __syncthreads();
    float lvar = 0.f;
    #pragma unroll
    for (int i = 0; i < 3; i++) { float d = vals[i] - mu; lvar += d * d; }
    red[tid] = lvar; __syncthreads();
    for (int off = 128; off > 0; off >>= 1) { if (tid < off) red[tid] += red[tid + off]; __syncthreads(); }
    const float rstd = rsqrtf(red[0] * (1.0f / D_) + 1e-12f);
    #pragma unroll
    for (int i = 0; i < 3; i++) {
        int c = tid + i * 256;
        out[(size_t)t * D_ + c] = (vals[i] - mu) * rstd * g[c] + bb[c];
    }
}

// ---------------- router: 1 wave per token
__global__ __launch_bounds__(64) void router_kernel(
    const float* __restrict__ att, const float* __restrict__ Wr,
    const float* __restrict__ br, float* __restrict__ gate, int* __restrict__ eidx)
{
    const int t = blockIdx.x;
    const int lane = threadIdx.x;
    float lg[E_] = {};
    for (int d = lane; d < D_; d += 64) {
        float xv = att[(size_t)t * D_ + d];
        #pragma unroll
        for (int e = 0; e < E_; e++) lg[e] += xv * Wr[d * E_ + e];
    }
    #pragma unroll
    for (int off = 32; off > 0; off >>= 1)
        #pragma unroll
        for (int e = 0; e < E_; e++) lg[e] += __shfl_down(lg[e], off);
    if (lane == 0) {
        float mx = -1e30f; int mi = 0;
        #pragma unroll
        for (int e = 0; e < E_; e++) {
            lg[e] += br[e];
            if (lg[e] > mx) { mx = lg[e]; mi = e; }
        }
        float ssum = 0.f;
        #pragma unroll
        for (int e = 0; e < E_; e++) ssum += expf(lg[e] - mx);
        gate[t] = 1.0f / ssum;
        eidx[t] = mi;
    }
}

// ---------------- position-within-expert scan (single block) + per-expert counts
__global__ __launch_bounds__(256) void pos_scan_kernel(
    const int* __restrict__ eidx, const float* __restrict__ gate,
    int* __restrict__ pos, float* __restrict__ scale, int* __restrict__ cnt_out)
{
    __shared__ int cnt[256][E_];
    const int tid = threadIdx.x;
    const int start = tid * (T_ / 256);
    int lc[E_] = {};
    for (int i = 0; i < T_ / 256; i++) lc[eidx[start + i]]++;
    #pragma unroll
    for (int e = 0; e < E_; e++) cnt[tid][e] = lc[e];
    __syncthreads();
    if (tid < E_) {
        int run = 0;
        for (int i = 0; i < 256; i++) { int c = cnt[i][tid]; cnt[i][tid] = run; run += c; }
        cnt_out[tid] = run;
    }
    __syncthreads();
    int off[E_];
    #pragma unroll
    for (int e = 0; e < E_; e++) off[e] = cnt[tid][e];
    for (int i = 0; i < T_ / 256; i++) {
        int tk = start + i;
        int e = eidx[tk];
        int p = off[e]++;
        bool keep = p < CAP_;
        pos[tk] = p < CAP_ - 1 ? p : CAP_ - 1;
        scale[tk] = keep ? gate[tk] : 0.0f;
    }
}

// ---------------- scatter kept tokens into per-expert bf16 buffers
__global__ __launch_bounds__(256) void scatter_kernel(
    const float* __restrict__ att, const int* __restrict__ eidx,
    const int* __restrict__ pos, const float* __restrict__ scale,
    bf16_t* __restrict__ buf)
{
    const int t = blockIdx.x;
    if (scale[t] == 0.0f) return;
    const int tid = threadIdx.x;
    const float* src = att + (size_t)t * D_;
    bf16_t* dst = buf + ((size_t)eidx[t] * CAP_ + pos[t]) * D_;
    for (int i = tid; i < D_; i += 256) dst[i] = (bf16_t)src[i];
}

// ---------------- gather (bf16 y) + residual + final LN
__global__ __launch_bounds__(256) void final_ln_kernel(
    const float* __restrict__ att, const bf16_t* __restrict__ y,
    const int* __restrict__ eidx, const int* __restrict__ pos,
    const float* __restrict__ scale,
    const float* __restrict__ g, const float* __restrict__ bb,
    float* __restrict__ out)
{
    const int t = blockIdx.x;
    const int tid = threadIdx.x;
    __shared__ float red[256];
    const float sc = scale[t];
    const bf16_t* yrow = y + ((size_t)eidx[t] * CAP_ + pos[t]) * D_;
    float vals[3];
    float lsum = 0.f;
    #pragma unroll
    for (int i = 0; i < 3; i++) {
        int c = tid + i * 256;
        float v = att[(size_t)t * D_ + c] + (float)yrow[c] * sc;
        vals[i] = v; lsum += v;
    }
    red[tid] = lsum; __syncthreads();
    for (int off = 128; off > 0; off >>= 1) { if (tid < off) red[tid] += red[tid + off]; __syncthreads(); }
    const float mu = red[0] * (1.0f / D_);
    __syncthreads();
    float lvar = 0.f;
    #pragma unroll
    for (int i = 0; i < 3; i++) { float d = vals[i] - mu; lvar += d * d; }
    red[tid] = lvar; __syncthreads();
    for (int off = 128; off > 0; off >>= 1) { if (tid < off) red[tid] += red[tid + off]; __syncthreads(); }
    const float rstd = rsqrtf(red[0] * (1.0f / D_) + 1e-12f);
    #pragma unroll
    for (int i = 0; i < 3; i++) {
        int c = tid + i * 256;
        out[(size_t)t * D_ + c] = (vals[i] - mu) * rstd * g[c] + bb[c];
    }
}

extern "C" void kernel_launch(void* const* d_in, const int* in_sizes, int n_in,
                              void* d_out, int out_size, void* d_ws, size_t ws_size,
                              hipStream_t stream) {
    const float* x     = (const float*)d_in[0];
    const float* mask  = (const float*)d_in[1];
    const float* Wq    = (const float*)d_in[2];
    const float* bq    = (const float*)d_in[3];
    const float* Wk    = (const float*)d_in[4];
    const float* bk    = (const float*)d_in[5];
    const float* Wv    = (const float*)d_in[6];
    const float* bv    = (const float*)d_in[7];
    const float* Wo    = (const float*)d_in[8];
    const float* bo    = (const float*)d_in[9];
    const float* ln1g  = (const float*)d_in[10];
    const float* ln1b  = (const float*)d_in[11];
    const float* Wr    = (const float*)d_in[12];
    const float* br    = (const float*)d_in[13];
    const float* W1    = (const float*)d_in[14];
    const float* b1    = (const float*)d_in[15];
    const float* W2    = (const float*)d_in[16];
    const float* b2    = (const float*)d_in[17];
    const float* ln2g  = (const float*)d_in[18];
    const float* ln2b  = (const float*)d_in[19];
    float* out = (float*)d_out;

    char* ws = (char*)d_ws;
    const size_t TDB = (size_t)T_ * D_ * 4;
    float* q_buf   = (float*)(ws);
    float* k_buf   = (float*)(ws + TDB);
    float* v_buf   = (float*)(ws + 2 * TDB);
    float* ctx_buf = (float*)(ws + 3 * TDB);
    float* att_buf = (float*)(ws + 4 * TDB);
    char*  smallp  = ws + 5 * TDB;
    float* gate_b  = (float*)(smallp);
    int*   eidx_b  = (int*)(smallp + 32768);
    int*   pos_b   = (int*)(smallp + 2 * 32768);
    float* scale_b = (float*)(smallp + 3 * 32768);
    int*   cnt_b   = (int*)(smallp + 4 * 32768);
    bf16_t* buf_b  = (bf16_t*)(smallp + 4 * 32768 + 128);
    bf16_t* y_b    = (bf16_t*)((char*)buf_b + (size_t)E_ * CAP_ * D_ * 2);
    bf16_t* W1T = (bf16_t*)(ws);
    bf16_t* W2T = (bf16_t*)(ws + (size_t)E_ * FF_ * D_ * 2);
    bf16_t* h_b = (bf16_t*)(ws + (size_t)2 * E_ * FF_ * D_ * 2);
    float* proj_b = q_buf;

    dim3 blk(256);
    // ---- attention path (fp32 — feeds the router, must stay accurate)
    gemm_f32_kernel<<<dim3(D_ / 128, T_ / 128), blk, 0, stream>>>(x, Wq, bq, q_buf, T_, D_, D_);
    gemm_f32_kernel<<<dim3(D_ / 128, T_ / 128), blk, 0, stream>>>(x, Wk, bk, k_buf, T_, D_, D_);
    gemm_f32_kernel<<<dim3(D_ / 128, T_ / 128), blk, 0, stream>>>(x, Wv, bv, v_buf, T_, D_, D_);
    flash_attn_kernel<<<dim3(S_ / 64, H_, B_), blk, 0, stream>>>(q_buf, k_buf, v_buf, mask, ctx_buf);
    gemm_f32_kernel<<<dim3(D_ / 128, T_ / 128), blk, 0, stream>>>(ctx_buf, Wo, bo, proj_b, T_, D_, D_);
    add_ln_kernel<<<dim3(T_), blk, 0, stream>>>(x, proj_b, ln1g, ln1b, att_buf);
    // ---- routing (fp32)
    router_kernel<<<dim3(T_), dim3(64), 0, stream>>>(att_buf, Wr, br, gate_b, eidx_b);
    pos_scan_kernel<<<dim3(1), blk, 0, stream>>>(eidx_b, gate_b, pos_b, scale_b, cnt_b);
    // ---- weight transpose-casts into dead q..ctx region (safe after add_ln)
    transpose_cast_kernel<<<dim3(FF_ / 32, D_ / 32, E_), blk, 0, stream>>>(W1, W1T, D_, FF_);
    transpose_cast_kernel<<<dim3(D_ / 32, FF_ / 32, E_), blk, 0, stream>>>(W2, W2T, FF_, D_);
    // ---- expert buffers
    hipMemsetAsync(buf_b, 0, (size_t)E_ * CAP_ * D_ * 2, stream);
    scatter_kernel<<<dim3(T_), blk, 0, stream>>>(att_buf, eidx_b, pos_b, scale_b, buf_b);
    // ---- expert FFNs, bf16 MFMA, 2 experts per z-batch
    for (int bch = 0; bch < 4; bch++) {
        const int e0 = bch * 2;
        mfma_gemm_kernel<<<dim3(FF_ / 128, CAP_ / 128, 2), blk, 0, stream>>>(
            buf_b + (size_t)e0 * CAP_ * D_, W1T + (size_t)e0 * FF_ * D_,
            b1 + (size_t)e0 * FF_, h_b,
            cnt_b, e0, CAP_, FF_, D_,
            (long)CAP_ * D_, (long)FF_ * D_, (long)FF_, (long)CAP_ * FF_, 1);
        mfma_gemm_kernel<<<dim3(D_ / 128, CAP_ / 128, 2), blk, 0, stream>>>(
            h_b, W2T + (size_t)e0 * D_ * FF_,
            b2 + (size_t)e0 * D_, y_b + (size_t)e0 * CAP_ * D_,
            cnt_b, e0, CAP_, D_, FF_,
            (long)CAP_ * FF_, (long)D_ * FF_, (long)D_, (long)CAP_ * D_, 0);
    }
    // ---- gather + residual + LN2
    final_ln_kernel<<<dim3(T_), blk, 0, stream>>>(att_buf, y_b, eidx_b, pos_b, scale_b, ln2g, ln2b, out);
}

// Round 5
// 1698.316 us; speedup vs baseline: 7.1059x; 1.0610x over previous
//
#include <hip/hip_runtime.h>
#include <hip/hip_bf16.h>
#include <math.h>

#define B_ 8
#define S_ 1024
#define D_ 768
#define H_ 12
#define DH_ 64
#define FF_ 3072
#define E_ 8
#define CAP_ 2048
#define T_ (B_ * S_)
#define QKVSTR 2304   // fused qkv row stride

typedef __bf16 bf16_t;
typedef bf16_t bf16x8_t __attribute__((ext_vector_type(8)));
typedef bf16_t bf16x4_t __attribute__((ext_vector_type(4)));
typedef float floatx4_t __attribute__((ext_vector_type(4)));

// ---------------- fp32 GEMM, 128x64 tile, 8x4 microtile, up to 3 fused weight mats
// C[M, grid.x*64] = A[M,K] @ {W0|W1|W2}[K,768] + bias; weight chosen by bx/12.
__global__ __launch_bounds__(256) void gemm3_f32_kernel(
    const float* __restrict__ A,
    const float* __restrict__ W0, const float* __restrict__ W1p, const float* __restrict__ W2p,
    const float* __restrict__ bias0, const float* __restrict__ bias1, const float* __restrict__ bias2,
    float* __restrict__ C, int K, int Cstride)
{
    __shared__ float As[16][132];   // As[k][m], m in 0..127
    __shared__ float Bs[16][68];    // Bs[k][n], n in 0..63
    const int bx = blockIdx.x;
    const int row0 = blockIdx.y * 128;
    const int wsel = bx / 12;
    const float* W = (wsel == 0) ? W0 : (wsel == 1) ? W1p : W2p;
    const float* bias = (wsel == 0) ? bias0 : (wsel == 1) ? bias1 : bias2;
    const int colg = (bx % 12) * 64;   // col within W (W row stride = 768)
    const int ccol0 = bx * 64;         // col in C

    const int tid = threadIdx.x;
    const int tx = tid & 15, ty = tid >> 4;
    float acc[8][4] = {};
    const int ar0 = tid >> 2, akc = (tid & 3) * 4;       // A staging chunk 0
    const int ar1 = (tid + 256) >> 2;                    // chunk 1 (same akc)
    const int bkk = tid >> 4, bnc = (tid & 15) * 4;      // B staging

    for (int k0 = 0; k0 < K; k0 += 16) {
        __syncthreads();
        {
            float4 va = *(const float4*)&A[(size_t)(row0 + ar0) * K + k0 + akc];
            As[akc + 0][ar0] = va.x; As[akc + 1][ar0] = va.y;
            As[akc + 2][ar0] = va.z; As[akc + 3][ar0] = va.w;
            float4 vb = *(const float4*)&A[(size_t)(row0 + ar1) * K + k0 + akc];
            As[akc + 0][ar1] = vb.x; As[akc + 1][ar1] = vb.y;
            As[akc + 2][ar1] = vb.z; As[akc + 3][ar1] = vb.w;
        }
        *(float4*)&Bs[bkk][bnc] = *(const float4*)&W[(size_t)(k0 + bkk) * 768 + colg + bnc];
        __syncthreads();
        #pragma unroll
        for (int kk = 0; kk < 16; kk++) {
            float4 a0 = *(float4*)&As[kk][ty * 8];
            float4 a1 = *(float4*)&As[kk][ty * 8 + 4];
            float4 b0 = *(float4*)&Bs[kk][tx * 4];
            const float am[8] = {a0.x, a0.y, a0.z, a0.w, a1.x, a1.y, a1.z, a1.w};
            const float bn[4] = {b0.x, b0.y, b0.z, b0.w};
            #pragma unroll
            for (int i = 0; i < 8; i++)
                #pragma unroll
                for (int j = 0; j < 4; j++)
                    acc[i][j] += am[i] * bn[j];
        }
    }
    const float4 bv = *(const float4*)&bias[colg + tx * 4];
    #pragma unroll
    for (int i = 0; i < 8; i++) {
        const int row = row0 + ty * 8 + i;
        float4 o;
        o.x = acc[i][0] + bv.x; o.y = acc[i][1] + bv.y;
        o.z = acc[i][2] + bv.z; o.w = acc[i][3] + bv.w;
        *(float4*)&C[(size_t)row * Cstride + ccol0 + tx * 4] = o;
    }
}

// ---------------- bf16 MFMA GEMM: C[M,N] = A[M,K] @ Bt[N,K]^T + bias (opt GELU), bf16 out
#define LSTR 40

__global__ __launch_bounds__(256) void mfma_gemm_kernel(
    const bf16_t* __restrict__ Abase, const bf16_t* __restrict__ Btbase,
    const float* __restrict__ biasbase, bf16_t* __restrict__ Cbase,
    const int* __restrict__ cnt, int cnt_off,
    int M, int N, int K,
    long strideAz, long strideBz, long strideBiasz, long strideCz,
    int apply_gelu)
{
    __shared__ bf16_t As[128 * LSTR];
    __shared__ bf16_t Bs[128 * LSTR];
    const int z = blockIdx.z;
    const int row0 = blockIdx.y * 128;
    const int col0 = blockIdx.x * 128;
    if (cnt && row0 >= cnt[cnt_off + z]) return;
    const bf16_t* A  = Abase + (size_t)z * strideAz;
    const bf16_t* Bt = Btbase + (size_t)z * strideBz;
    const float* bias = biasbase + (size_t)z * strideBiasz;
    bf16_t* C = Cbase + (size_t)z * strideCz;

    const int tid = threadIdx.x;
    const int lane = tid & 63, wave = tid >> 6;
    const int wm = (wave >> 1) * 64, wn = (wave & 1) * 64;
    const int l16 = lane & 15, quad = lane >> 4;

    floatx4_t acc[4][4] = {};

    const int ch0 = tid, ch1 = tid + 256;
    const int r0a = ch0 >> 2, kc0 = (ch0 & 3) * 8;
    const int r1a = ch1 >> 2, kc1 = (ch1 & 3) * 8;

    for (int k0 = 0; k0 < K; k0 += 32) {
        __syncthreads();
        *(int4*)&As[r0a * LSTR + kc0] = *(const int4*)&A[(size_t)(row0 + r0a) * K + k0 + kc0];
        *(int4*)&As[r1a * LSTR + kc1] = *(const int4*)&A[(size_t)(row0 + r1a) * K + k0 + kc1];
        *(int4*)&Bs[r0a * LSTR + kc0] = *(const int4*)&Bt[(size_t)(col0 + r0a) * K + k0 + kc0];
        *(int4*)&Bs[r1a * LSTR + kc1] = *(const int4*)&Bt[(size_t)(col0 + r1a) * K + k0 + kc1];
        __syncthreads();
        bf16x8_t a[4], b[4];
        #pragma unroll
        for (int mt = 0; mt < 4; mt++)
            a[mt] = *(bf16x8_t*)&As[(wm + mt * 16 + l16) * LSTR + quad * 8];
        #pragma unroll
        for (int nt = 0; nt < 4; nt++)
            b[nt] = *(bf16x8_t*)&Bs[(wn + nt * 16 + l16) * LSTR + quad * 8];
        #pragma unroll
        for (int mt = 0; mt < 4; mt++)
            #pragma unroll
            for (int nt = 0; nt < 4; nt++)
                acc[mt][nt] = __builtin_amdgcn_mfma_f32_16x16x32_bf16(a[mt], b[nt], acc[mt][nt], 0, 0, 0);
    }

    #pragma unroll
    for (int mt = 0; mt < 4; mt++) {
        #pragma unroll
        for (int nt = 0; nt < 4; nt++) {
            const int col = col0 + wn + nt * 16 + l16;
            const float bv = bias[col];
            #pragma unroll
            for (int r = 0; r < 4; r++) {
                const int row = row0 + wm + mt * 16 + quad * 4 + r;
                float v = acc[mt][nt][r] + bv;
                if (apply_gelu) v = 0.5f * v * (1.0f + erff(v * 0.70710678118654752f));
                C[(size_t)row * N + col] = (bf16_t)v;
            }
        }
    }
}

// ---------------- transpose + cast: fp32 src[R,C] -> bf16 dst[C,R], z-batched
__global__ __launch_bounds__(256) void transpose_cast_kernel(
    const float* __restrict__ src, bf16_t* __restrict__ dst, int R, int C)
{
    __shared__ float tile[32][33];
    const size_t zoff = (size_t)blockIdx.z * R * C;
    const float* s = src + zoff;
    bf16_t* d = dst + zoff;
    const int r0 = blockIdx.y * 32, c0 = blockIdx.x * 32;
    const int tid = threadIdx.x;
    const int tr = tid >> 3, tc4 = (tid & 7) * 4;
    float4 v = *(const float4*)&s[(size_t)(r0 + tr) * C + c0 + tc4];
    tile[tr][tc4 + 0] = v.x; tile[tr][tc4 + 1] = v.y;
    tile[tr][tc4 + 2] = v.z; tile[tr][tc4 + 3] = v.w;
    __syncthreads();
    const int cc = tid >> 3, rr4 = (tid & 7) * 4;
    bf16x4_t o;
    #pragma unroll
    for (int i = 0; i < 4; i++) o[i] = (bf16_t)tile[rr4 + i][cc];
    *(bf16x4_t*)&d[(size_t)(c0 + cc) * R + r0 + rr4] = o;
}

// ---------------- flash-style attention on fused qkv buffer [T, 2304]
#define AS 68

__global__ __launch_bounds__(256) void flash_attn_kernel(
    const float* __restrict__ qkv, const float* __restrict__ mask,
    float* __restrict__ ctx)
{
    __shared__ float Qs[64 * AS];
    __shared__ float Ks[64 * AS];    // holds K tile, then reused for P
    __shared__ float VsT[64 * AS];
    const int qt = blockIdx.x, h = blockIdx.y, b = blockIdx.z;
    const int tid = threadIdx.x;
    const int tx = tid & 15, ty = tid >> 4;
    const int q0 = qt * 64;
    const size_t hb = (size_t)b * S_ * QKVSTR + (size_t)h * DH_;  // q base; +768 k; +1536 v

    #pragma unroll
    for (int i = 0; i < 4; i++) {
        int idx = i * 256 + tid;
        int r = idx >> 4, fc = idx & 15;
        *(float4*)&Qs[r * AS + fc * 4] =
            *(const float4*)&qkv[hb + (size_t)(q0 + r) * QKVSTR + fc * 4];
    }

    float O[4][4] = {};
    float mrun[4], lrun[4];
    #pragma unroll
    for (int i = 0; i < 4; i++) { mrun[i] = -1e30f; lrun[i] = 0.f; }

    for (int kt = 0; kt < S_ / 64; kt++) {
        const int k0 = kt * 64;
        __syncthreads();
        #pragma unroll
        for (int i = 0; i < 4; i++) {
            int idx = i * 256 + tid;
            int r = idx >> 4, fc = idx & 15;
            *(float4*)&Ks[r * AS + fc * 4] =
                *(const float4*)&qkv[hb + 768 + (size_t)(k0 + r) * QKVSTR + fc * 4];
        }
        #pragma unroll
        for (int i = 0; i < 16; i++) {
            int idx = i * 256 + tid;
            int key = idx >> 6, d = idx & 63;
            VsT[d * AS + key] = qkv[hb + 1536 + (size_t)(k0 + key) * QKVSTR + d];
        }
        __syncthreads();

        float acc[4][4] = {};
        #pragma unroll 4
        for (int d0 = 0; d0 < DH_; d0 += 4) {
            float4 a4[4], b4[4];
            #pragma unroll
            for (int i = 0; i < 4; i++) a4[i] = *(float4*)&Qs[(ty * 4 + i) * AS + d0];
            #pragma unroll
            for (int j = 0; j < 4; j++) b4[j] = *(float4*)&Ks[(tx + 16 * j) * AS + d0];
            #pragma unroll
            for (int i = 0; i < 4; i++)
                #pragma unroll
                for (int j = 0; j < 4; j++)
                    acc[i][j] += a4[i].x * b4[j].x + a4[i].y * b4[j].y
                               + a4[i].z * b4[j].z + a4[i].w * b4[j].w;
        }
        float mk[4];
        #pragma unroll
        for (int j = 0; j < 4; j++) mk[j] = mask[b * S_ + k0 + tx + 16 * j];

        __syncthreads();

        #pragma unroll
        for (int i = 0; i < 4; i++) {
            float s[4];
            float rmax = -1e30f;
            #pragma unroll
            for (int j = 0; j < 4; j++) {
                s[j] = acc[i][j] * 0.125f + mk[j];
                rmax = fmaxf(rmax, s[j]);
            }
            #pragma unroll
            for (int off = 1; off < 16; off <<= 1) rmax = fmaxf(rmax, __shfl_xor(rmax, off));
            const float mnew = fmaxf(mrun[i], rmax);
            const float alpha = __expf(mrun[i] - mnew);
            float rsum = 0.f;
            #pragma unroll
            for (int j = 0; j < 4; j++) {
                float p = __expf(s[j] - mnew);
                Ks[(ty * 4 + i) * AS + tx + 16 * j] = p;
                rsum += p;
            }
            #pragma unroll
            for (int off = 1; off < 16; off <<= 1) rsum += __shfl_xor(rsum, off);
            lrun[i] = lrun[i] * alpha + rsum;
            mrun[i] = mnew;
            #pragma unroll
            for (int j = 0; j < 4; j++) O[i][j] *= alpha;
        }
        __syncthreads();

        #pragma unroll 4
        for (int c0 = 0; c0 < 64; c0 += 4) {
            float4 a4[4], b4[4];
            #pragma unroll
            for (int i = 0; i < 4; i++) a4[i] = *(float4*)&Ks[(ty * 4 + i) * AS + c0];
            #pragma unroll
            for (int j = 0; j < 4; j++) b4[j] = *(float4*)&VsT[(tx + 16 * j) * AS + c0];
            #pragma unroll
            for (int i = 0; i < 4; i++)
                #pragma unroll
                for (int j = 0; j < 4; j++)
                    O[i][j] += a4[i].x * b4[j].x + a4[i].y * b4[j].y
                             + a4[i].z * b4[j].z + a4[i].w * b4[j].w;
        }
    }

    const size_t cb = (size_t)b * S_ * D_ + (size_t)h * DH_;
    #pragma unroll
    for (int i = 0; i < 4; i++) {
        const float invl = 1.0f / lrun[i];
        #pragma unroll
        for (int j = 0; j < 4; j++)
            ctx[cb + (size_t)(q0 + ty * 4 + i) * D_ + tx + 16 * j] = O[i][j] * invl;
    }
}

// ---------------- out[t] = LN(x[t] + y[t]) * g + b
__global__ __launch_bounds__(256) void add_ln_kernel(
    const float* __restrict__ x, const float* __restrict__ y,
    const float* __restrict__ g, const float* __restrict__ bb,
    float* __restrict__ out)
{
    const int t = blockIdx.x;
    const int tid = threadIdx.x;
    __shared__ float red[256];
    float vals[3];
    float lsum = 0.f;
    #pragma unroll
    for (int i = 0; i < 3; i++) {
        int c = tid + i * 256;
        float v = x[(size_t)t * D_ + c] + y[(size_t)t * D_ + c];
        vals[i] = v; lsum += v;
    }
    red[tid] = lsum; __syncthreads();
    for (int off = 128; off > 0; off >>= 1) { if (tid < off) red[tid] += red[tid + off]; __syncthreads(); }
    const float mu = red[0] * (1.0f / D_);
    __syncthreads();
    float lvar = 0.f;
    #pragma unroll
    for (int i = 0; i < 3; i++) { float d = vals[i] - mu; lvar += d * d; }
    red[tid] = lvar; __syncthreads();
    for (int off = 128; off > 0; off >>= 1) { if (tid < off) red[tid] += red[tid + off]; __syncthreads(); }
    const float rstd = rsqrtf(red[0] * (1.0f / D_) + 1e-12f);
    #pragma unroll
    for (int i = 0; i < 3; i++) {
        int c = tid + i * 256;
        out[(size_t)t * D_ + c] = (vals[i] - mu) * rstd * g[c] + bb[c];
    }
}

// ---------------- router: 1 wave per token
__global__ __launch_bounds__(64) void router_kernel(
    const float* __restrict__ att, const float* __restrict__ Wr,
    const float* __restrict__ br, float* __restrict__ gate, int* __restrict__ eidx)
{
    const int t = blockIdx.x;
    const int lane = threadIdx.x;
    float lg[E_] = {};
    for (int d = lane; d < D_; d += 64) {
        float xv = att[(size_t)t * D_ + d];
        #pragma unroll
        for (int e = 0; e < E_; e++) lg[e] += xv * Wr[d * E_ + e];
    }
    #pragma unroll
    for (int off = 32; off > 0; off >>= 1)
        #pragma unroll
        for (int e = 0; e < E_; e++) lg[e] += __shfl_down(lg[e], off);
    if (lane == 0) {
        float mx = -1e30f; int mi = 0;
        #pragma unroll
        for (int e = 0; e < E_; e++) {
            lg[e] += br[e];
            if (lg[e] > mx) { mx = lg[e]; mi = e; }
        }
        float ssum = 0.f;
        #pragma unroll
        for (int e = 0; e < E_; e++) ssum += expf(lg[e] - mx);
        gate[t] = 1.0f / ssum;
        eidx[t] = mi;
    }
}

// ---------------- position-within-expert scan (single block) + per-expert counts
__global__ __launch_bounds__(256) void pos_scan_kernel(
    const int* __restrict__ eidx, const float* __restrict__ gate,
    int* __restrict__ pos, float* __restrict__ scale, int* __restrict__ cnt_out)
{
    __shared__ int cnt[256][E_];
    const int tid = threadIdx.x;
    const int start = tid * (T_ / 256);
    int lc[E_] = {};
    for (int i = 0; i < T_ / 256; i++) lc[eidx[start + i]]++;
    #pragma unroll
    for (int e = 0; e < E_; e++) cnt[tid][e] = lc[e];
    __syncthreads();
    if (tid < E_) {
        int run = 0;
        for (int i = 0; i < 256; i++) { int c = cnt[i][tid]; cnt[i][tid] = run; run += c; }
        cnt_out[tid] = run;
    }
    __syncthreads();
    int off[E_];
    #pragma unroll
    for (int e = 0; e < E_; e++) off[e] = cnt[tid][e];
    for (int i = 0; i < T_ / 256; i++) {
        int tk = start + i;
        int e = eidx[tk];
        int p = off[e]++;
        bool keep = p < CAP_;
        pos[tk] = p < CAP_ - 1 ? p : CAP_ - 1;
        scale[tk] = keep ? gate[tk] : 0.0f;
    }
}

// ---------------- scatter kept tokens into per-expert bf16 buffers
__global__ __launch_bounds__(256) void scatter_kernel(
    const float* __restrict__ att, const int* __restrict__ eidx,
    const int* __restrict__ pos, const float* __restrict__ scale,
    bf16_t* __restrict__ buf)
{
    const int t = blockIdx.x;
    if (scale[t] == 0.0f) return;
    const int tid = threadIdx.x;
    const float* src = att + (size_t)t * D_;
    bf16_t* dst = buf + ((size_t)eidx[t] * CAP_ + pos[t]) * D_;
    for (int i = tid; i < D_; i += 256) dst[i] = (bf16_t)src[i];
}

// ---------------- gather (bf16 y) + residual + final LN
__global__ __launch_bounds__(256) void final_ln_kernel(
    const float* __restrict__ att, const bf16_t* __restrict__ y,
    const int* __restrict__ eidx, const int* __restrict__ pos,
    const float* __restrict__ scale,
    const float* __restrict__ g, const float* __restrict__ bb,
    float* __restrict__ out)
{
    const int t = blockIdx.x;
    const int tid = threadIdx.x;
    __shared__ float red[256];
    const float sc = scale[t];
    const bf16_t* yrow = y + ((size_t)eidx[t] * CAP_ + pos[t]) * D_;
    float vals[3];
    float lsum = 0.f;
    #pragma unroll
    for (int i = 0; i < 3; i++) {
        int c = tid + i * 256;
        float v = att[(size_t)t * D_ + c] + (float)yrow[c] * sc;
        vals[i] = v; lsum += v;
    }
    red[tid] = lsum; __syncthreads();
    for (int off = 128; off > 0; off >>= 1) { if (tid < off) red[tid] += red[tid + off]; __syncthreads(); }
    const float mu = red[0] * (1.0f / D_);
    __syncthreads();
    float lvar = 0.f;
    #pragma unroll
    for (int i = 0; i < 3; i++) { float d = vals[i] - mu; lvar += d * d; }
    red[tid] = lvar; __syncthreads();
    for (int off = 128; off > 0; off >>= 1) { if (tid < off) red[tid] += red[tid + off]; __syncthreads(); }
    const float rstd = rsqrtf(red[0] * (1.0f / D_) + 1e-12f);
    #pragma unroll
    for (int i = 0; i < 3; i++) {
        int c = tid + i * 256;
        out[(size_t)t * D_ + c] = (vals[i] - mu) * rstd * g[c] + bb[c];
    }
}

extern "C" void kernel_launch(void* const* d_in, const int* in_sizes, int n_in,
                              void* d_out, int out_size, void* d_ws, size_t ws_size,
                              hipStream_t stream) {
    const float* x     = (const float*)d_in[0];
    const float* mask  = (const float*)d_in[1];
    const float* Wq    = (const float*)d_in[2];
    const float* bq    = (const float*)d_in[3];
    const float* Wk    = (const float*)d_in[4];
    const float* bk    = (const float*)d_in[5];
    const float* Wv    = (const float*)d_in[6];
    const float* bv    = (const float*)d_in[7];
    const float* Wo    = (const float*)d_in[8];
    const float* bo    = (const float*)d_in[9];
    const float* ln1g  = (const float*)d_in[10];
    const float* ln1b  = (const float*)d_in[11];
    const float* Wr    = (const float*)d_in[12];
    const float* br    = (const float*)d_in[13];
    const float* W1    = (const float*)d_in[14];
    const float* b1    = (const float*)d_in[15];
    const float* W2    = (const float*)d_in[16];
    const float* b2    = (const float*)d_in[17];
    const float* ln2g  = (const float*)d_in[18];
    const float* ln2b  = (const float*)d_in[19];
    float* out = (float*)d_out;

    char* ws = (char*)d_ws;
    const size_t TDB = (size_t)T_ * D_ * 4;
    float* qkv_buf = (float*)(ws);                       // [T,2304] fp32 (3 TDB)
    float* ctx_buf = (float*)(ws + 3 * TDB);
    float* att_buf = (float*)(ws + 4 * TDB);
    char*  smallp  = ws + 5 * TDB;
    float* gate_b  = (float*)(smallp);
    int*   eidx_b  = (int*)(smallp + 32768);
    int*   pos_b   = (int*)(smallp + 2 * 32768);
    float* scale_b = (float*)(smallp + 3 * 32768);
    int*   cnt_b   = (int*)(smallp + 4 * 32768);
    bf16_t* buf_b  = (bf16_t*)(smallp + 4 * 32768 + 128);
    bf16_t* y_b    = (bf16_t*)((char*)buf_b + (size_t)E_ * CAP_ * D_ * 2);
    // overlays of the qkv..ctx region (dead after add_ln):
    bf16_t* W1T = (bf16_t*)(ws);
    bf16_t* W2T = (bf16_t*)(ws + (size_t)E_ * FF_ * D_ * 2);
    bf16_t* h_b = (bf16_t*)(ws + (size_t)2 * E_ * FF_ * D_ * 2);
    float* proj_b = qkv_buf;   // [T,D] reuse (qkv dead after flash)

    dim3 blk(256);
    // ---- attention path (fp32 — feeds the router, must stay accurate)
    gemm3_f32_kernel<<<dim3(36, T_ / 128), blk, 0, stream>>>(
        x, Wq, Wk, Wv, bq, bk, bv, qkv_buf, D_, QKVSTR);
    flash_attn_kernel<<<dim3(S_ / 64, H_, B_), blk, 0, stream>>>(qkv_buf, mask, ctx_buf);
    gemm3_f32_kernel<<<dim3(12, T_ / 128), blk, 0, stream>>>(
        ctx_buf, Wo, Wo, Wo, bo, bo, bo, proj_b, D_, D_);
    add_ln_kernel<<<dim3(T_), blk, 0, stream>>>(x, proj_b, ln1g, ln1b, att_buf);
    // ---- routing (fp32)
    router_kernel<<<dim3(T_), dim3(64), 0, stream>>>(att_buf, Wr, br, gate_b, eidx_b);
    pos_scan_kernel<<<dim3(1), blk, 0, stream>>>(eidx_b, gate_b, pos_b, scale_b, cnt_b);
    // ---- weight transpose-casts into dead qkv..ctx region (safe after add_ln)
    transpose_cast_kernel<<<dim3(FF_ / 32, D_ / 32, E_), blk, 0, stream>>>(W1, W1T, D_, FF_);
    transpose_cast_kernel<<<dim3(D_ / 32, FF_ / 32, E_), blk, 0, stream>>>(W2, W2T, FF_, D_);
    // ---- expert buffers
    hipMemsetAsync(buf_b, 0, (size_t)E_ * CAP_ * D_ * 2, stream);
    scatter_kernel<<<dim3(T_), blk, 0, stream>>>(att_buf, eidx_b, pos_b, scale_b, buf_b);
    // ---- expert FFNs, bf16 MFMA, 2 experts per z-batch
    for (int bch = 0; bch < 4; bch++) {
        const int e0 = bch * 2;
        mfma_gemm_kernel<<<dim3(FF_ / 128, CAP_ / 128, 2), blk, 0, stream>>>(
            buf_b + (size_t)e0 * CAP_ * D_, W1T + (size_t)e0 * FF_ * D_,
            b1 + (size_t)e0 * FF_, h_b,
            cnt_b, e0, CAP_, FF_, D_,
            (long)CAP_ * D_, (long)FF_ * D_, (long)FF_, (long)CAP_ * FF_, 1);
        mfma_gemm_kernel<<<dim3(D_ / 128, CAP_ / 128, 2), blk, 0, stream>>>(
            h_b, W2T + (size_t)e0 * D_ * FF_,
            b2 + (size_t)e0 * D_, y_b + (size_t)e0 * CAP_ * D_,
            cnt_b, e0, CAP_, D_, FF_,
            (long)CAP_ * FF_, (long)D_ * FF_, (long)D_, (long)CAP_ * D_, 0);
    }
    // ---- gather + residual + LN2
    final_ln_kernel<<<dim3(T_), blk, 0, stream>>>(att_buf, y_b, eidx_b, pos_b, scale_b, ln2g, ln2b, out);
}

// Round 6
// 1426.299 us; speedup vs baseline: 8.4611x; 1.1907x over previous
//
#include <hip/hip_runtime.h>
#include <hip/hip_bf16.h>
#include <math.h>

#define B_ 8
#define S_ 1024
#define D_ 768
#define H_ 12
#define DH_ 64
#define FF_ 3072
#define E_ 8
#define CAP_ 2048
#define T_ (B_ * S_)
#define QKVSTR 2304   // fused qkv row stride

typedef __bf16 bf16_t;
typedef bf16_t bf16x8_t __attribute__((ext_vector_type(8)));
typedef bf16_t bf16x4_t __attribute__((ext_vector_type(4)));
typedef float floatx4_t __attribute__((ext_vector_type(4)));
typedef _Float16 f16_t;
typedef f16_t f16x8_t __attribute__((ext_vector_type(8)));
typedef f16_t f16x4_t __attribute__((ext_vector_type(4)));

// ---------------- fp32 GEMM, 128x64 tile, 8x4 microtile, up to 3 fused weight mats
__global__ __launch_bounds__(256) void gemm3_f32_kernel(
    const float* __restrict__ A,
    const float* __restrict__ W0, const float* __restrict__ W1p, const float* __restrict__ W2p,
    const float* __restrict__ bias0, const float* __restrict__ bias1, const float* __restrict__ bias2,
    float* __restrict__ C, int K, int Cstride)
{
    __shared__ float As[16][132];   // As[k][m], m in 0..127
    __shared__ float Bs[16][68];    // Bs[k][n], n in 0..63
    const int bx = blockIdx.x;
    const int row0 = blockIdx.y * 128;
    const int wsel = bx / 12;
    const float* W = (wsel == 0) ? W0 : (wsel == 1) ? W1p : W2p;
    const float* bias = (wsel == 0) ? bias0 : (wsel == 1) ? bias1 : bias2;
    const int colg = (bx % 12) * 64;   // col within W (W row stride = 768)
    const int ccol0 = bx * 64;         // col in C

    const int tid = threadIdx.x;
    const int tx = tid & 15, ty = tid >> 4;
    float acc[8][4] = {};
    const int ar0 = tid >> 2, akc = (tid & 3) * 4;
    const int ar1 = (tid + 256) >> 2;
    const int bkk = tid >> 4, bnc = (tid & 15) * 4;

    for (int k0 = 0; k0 < K; k0 += 16) {
        __syncthreads();
        {
            float4 va = *(const float4*)&A[(size_t)(row0 + ar0) * K + k0 + akc];
            As[akc + 0][ar0] = va.x; As[akc + 1][ar0] = va.y;
            As[akc + 2][ar0] = va.z; As[akc + 3][ar0] = va.w;
            float4 vb = *(const float4*)&A[(size_t)(row0 + ar1) * K + k0 + akc];
            As[akc + 0][ar1] = vb.x; As[akc + 1][ar1] = vb.y;
            As[akc + 2][ar1] = vb.z; As[akc + 3][ar1] = vb.w;
        }
        *(float4*)&Bs[bkk][bnc] = *(const float4*)&W[(size_t)(k0 + bkk) * 768 + colg + bnc];
        __syncthreads();
        #pragma unroll
        for (int kk = 0; kk < 16; kk++) {
            float4 a0 = *(float4*)&As[kk][ty * 8];
            float4 a1 = *(float4*)&As[kk][ty * 8 + 4];
            float4 b0 = *(float4*)&Bs[kk][tx * 4];
            const float am[8] = {a0.x, a0.y, a0.z, a0.w, a1.x, a1.y, a1.z, a1.w};
            const float bn[4] = {b0.x, b0.y, b0.z, b0.w};
            #pragma unroll
            for (int i = 0; i < 8; i++)
                #pragma unroll
                for (int j = 0; j < 4; j++)
                    acc[i][j] += am[i] * bn[j];
        }
    }
    const float4 bv = *(const float4*)&bias[colg + tx * 4];
    #pragma unroll
    for (int i = 0; i < 8; i++) {
        const int row = row0 + ty * 8 + i;
        float4 o;
        o.x = acc[i][0] + bv.x; o.y = acc[i][1] + bv.y;
        o.z = acc[i][2] + bv.z; o.w = acc[i][3] + bv.w;
        *(float4*)&C[(size_t)row * Cstride + ccol0 + tx * 4] = o;
    }
}

// ---------------- bf16 MFMA GEMM: C[M,N] = A[M,K] @ Bt[N,K]^T + bias (opt GELU), bf16 out
#define LSTR 40

__global__ __launch_bounds__(256) void mfma_gemm_kernel(
    const bf16_t* __restrict__ Abase, const bf16_t* __restrict__ Btbase,
    const float* __restrict__ biasbase, bf16_t* __restrict__ Cbase,
    const int* __restrict__ cnt, int cnt_off,
    int M, int N, int K,
    long strideAz, long strideBz, long strideBiasz, long strideCz,
    int apply_gelu)
{
    __shared__ bf16_t As[128 * LSTR];
    __shared__ bf16_t Bs[128 * LSTR];
    const int z = blockIdx.z;
    const int row0 = blockIdx.y * 128;
    const int col0 = blockIdx.x * 128;
    if (cnt && row0 >= cnt[cnt_off + z]) return;
    const bf16_t* A  = Abase + (size_t)z * strideAz;
    const bf16_t* Bt = Btbase + (size_t)z * strideBz;
    const float* bias = biasbase + (size_t)z * strideBiasz;
    bf16_t* C = Cbase + (size_t)z * strideCz;

    const int tid = threadIdx.x;
    const int lane = tid & 63, wave = tid >> 6;
    const int wm = (wave >> 1) * 64, wn = (wave & 1) * 64;
    const int l16 = lane & 15, quad = lane >> 4;

    floatx4_t acc[4][4] = {};

    const int ch0 = tid, ch1 = tid + 256;
    const int r0a = ch0 >> 2, kc0 = (ch0 & 3) * 8;
    const int r1a = ch1 >> 2, kc1 = (ch1 & 3) * 8;

    for (int k0 = 0; k0 < K; k0 += 32) {
        __syncthreads();
        *(int4*)&As[r0a * LSTR + kc0] = *(const int4*)&A[(size_t)(row0 + r0a) * K + k0 + kc0];
        *(int4*)&As[r1a * LSTR + kc1] = *(const int4*)&A[(size_t)(row0 + r1a) * K + k0 + kc1];
        *(int4*)&Bs[r0a * LSTR + kc0] = *(const int4*)&Bt[(size_t)(col0 + r0a) * K + k0 + kc0];
        *(int4*)&Bs[r1a * LSTR + kc1] = *(const int4*)&Bt[(size_t)(col0 + r1a) * K + k0 + kc1];
        __syncthreads();
        bf16x8_t a[4], b[4];
        #pragma unroll
        for (int mt = 0; mt < 4; mt++)
            a[mt] = *(bf16x8_t*)&As[(wm + mt * 16 + l16) * LSTR + quad * 8];
        #pragma unroll
        for (int nt = 0; nt < 4; nt++)
            b[nt] = *(bf16x8_t*)&Bs[(wn + nt * 16 + l16) * LSTR + quad * 8];
        #pragma unroll
        for (int mt = 0; mt < 4; mt++)
            #pragma unroll
            for (int nt = 0; nt < 4; nt++)
                acc[mt][nt] = __builtin_amdgcn_mfma_f32_16x16x32_bf16(a[mt], b[nt], acc[mt][nt], 0, 0, 0);
    }

    #pragma unroll
    for (int mt = 0; mt < 4; mt++) {
        #pragma unroll
        for (int nt = 0; nt < 4; nt++) {
            const int col = col0 + wn + nt * 16 + l16;
            const float bv = bias[col];
            #pragma unroll
            for (int r = 0; r < 4; r++) {
                const int row = row0 + wm + mt * 16 + quad * 4 + r;
                float v = acc[mt][nt][r] + bv;
                if (apply_gelu) v = 0.5f * v * (1.0f + erff(v * 0.70710678118654752f));
                C[(size_t)row * N + col] = (bf16_t)v;
            }
        }
    }
}

// ---------------- transpose + cast: fp32 src[R,C] -> bf16 dst[C,R], z-batched
__global__ __launch_bounds__(256) void transpose_cast_kernel(
    const float* __restrict__ src, bf16_t* __restrict__ dst, int R, int C)
{
    __shared__ float tile[32][33];
    const size_t zoff = (size_t)blockIdx.z * R * C;
    const float* s = src + zoff;
    bf16_t* d = dst + zoff;
    const int r0 = blockIdx.y * 32, c0 = blockIdx.x * 32;
    const int tid = threadIdx.x;
    const int tr = tid >> 3, tc4 = (tid & 7) * 4;
    float4 v = *(const float4*)&s[(size_t)(r0 + tr) * C + c0 + tc4];
    tile[tr][tc4 + 0] = v.x; tile[tr][tc4 + 1] = v.y;
    tile[tr][tc4 + 2] = v.z; tile[tr][tc4 + 3] = v.w;
    __syncthreads();
    const int cc = tid >> 3, rr4 = (tid & 7) * 4;
    bf16x4_t o;
    #pragma unroll
    for (int i = 0; i < 4; i++) o[i] = (bf16_t)tile[rr4 + i][cc];
    *(bf16x4_t*)&d[(size_t)(c0 + cc) * R + r0 + rr4] = o;
}

// ---------------- flash attention via split-f16 MFMA (fp32-equivalent precision)
// x = h + l (h=(half)x, l=(half)(x-h)); a*b ~= ah*bh + al*bh + ah*bl, fp32 MFMA accum.
#define FSTR 72   // LDS row stride (f16 elems): 144 B rows, 16B-aligned, ~2-way banks

__global__ __launch_bounds__(256) void flash_attn_mfma_kernel(
    const float* __restrict__ qkv, const float* __restrict__ mask,
    float* __restrict__ ctx)
{
    __shared__ f16_t Qh[64 * FSTR], Ql[64 * FSTR];
    __shared__ f16_t Kh[64 * FSTR], Kl[64 * FSTR];
    __shared__ f16_t VTh[64 * FSTR], VTl[64 * FSTR];   // VT[dh][key]
    __shared__ f16_t Ph[64 * FSTR], Pl[64 * FSTR];
    const int qt = blockIdx.x, h = blockIdx.y, b = blockIdx.z;
    const int tid = threadIdx.x;
    const int lane = tid & 63, wave = tid >> 6;
    const int l16 = lane & 15, quad = lane >> 4;
    const int wm = wave * 16;           // wave's 16-query-row strip
    const int q0 = qt * 64;
    const size_t hb = (size_t)b * S_ * QKVSTR + (size_t)h * DH_;  // q; +768 k; +1536 v

    // ---- stage Q (once), split h/l
    #pragma unroll
    for (int i = 0; i < 4; i++) {
        int idx = i * 256 + tid;            // 0..1023
        int r = idx >> 4, fc = idx & 15;
        float4 v = *(const float4*)&qkv[hb + (size_t)(q0 + r) * QKVSTR + fc * 4];
        f16x4_t vh, vl;
        const float vv[4] = {v.x, v.y, v.z, v.w};
        #pragma unroll
        for (int c = 0; c < 4; c++) {
            f16_t hi = (f16_t)vv[c];
            vh[c] = hi; vl[c] = (f16_t)(vv[c] - (float)hi);
        }
        *(f16x4_t*)&Qh[r * FSTR + fc * 4] = vh;
        *(f16x4_t*)&Ql[r * FSTR + fc * 4] = vl;
    }

    floatx4_t Oacc[4] = {};             // [nt], C-layout: col=nt*16+l16, row=wm+quad*4+r
    float mrun[4], lrun[4];
    #pragma unroll
    for (int i = 0; i < 4; i++) { mrun[i] = -1e30f; lrun[i] = 0.f; }

    for (int kt = 0; kt < S_ / 64; kt++) {
        const int k0 = kt * 64;
        __syncthreads();   // prior QK/PV readers of K/V/P done
        // stage K split
        #pragma unroll
        for (int i = 0; i < 4; i++) {
            int idx = i * 256 + tid;
            int r = idx >> 4, fc = idx & 15;
            float4 v = *(const float4*)&qkv[hb + 768 + (size_t)(k0 + r) * QKVSTR + fc * 4];
            f16x4_t vh, vl;
            const float vv[4] = {v.x, v.y, v.z, v.w};
            #pragma unroll
            for (int c = 0; c < 4; c++) {
                f16_t hi = (f16_t)vv[c];
                vh[c] = hi; vl[c] = (f16_t)(vv[c] - (float)hi);
            }
            *(f16x4_t*)&Kh[r * FSTR + fc * 4] = vh;
            *(f16x4_t*)&Kl[r * FSTR + fc * 4] = vl;
        }
        // stage V transposed, split
        #pragma unroll
        for (int i = 0; i < 16; i++) {
            int idx = i * 256 + tid;
            int key = idx >> 6, d = idx & 63;
            float v = qkv[hb + 1536 + (size_t)(k0 + key) * QKVSTR + d];
            f16_t hi = (f16_t)v;
            VTh[d * FSTR + key] = hi;
            VTl[d * FSTR + key] = (f16_t)(v - (float)hi);
        }
        __syncthreads();

        // ---- S = Q @ K^T, 4 col-tiles of 16, 3-product split
        floatx4_t sacc[4] = {};
        #pragma unroll
        for (int ks = 0; ks < 64; ks += 32) {
            f16x8_t ah = *(f16x8_t*)&Qh[(wm + l16) * FSTR + ks + quad * 8];
            f16x8_t al = *(f16x8_t*)&Ql[(wm + l16) * FSTR + ks + quad * 8];
            #pragma unroll
            for (int nt = 0; nt < 4; nt++) {
                f16x8_t bh = *(f16x8_t*)&Kh[(nt * 16 + l16) * FSTR + ks + quad * 8];
                f16x8_t bl = *(f16x8_t*)&Kl[(nt * 16 + l16) * FSTR + ks + quad * 8];
                sacc[nt] = __builtin_amdgcn_mfma_f32_16x16x32_f16(ah, bh, sacc[nt], 0, 0, 0);
                sacc[nt] = __builtin_amdgcn_mfma_f32_16x16x32_f16(al, bh, sacc[nt], 0, 0, 0);
                sacc[nt] = __builtin_amdgcn_mfma_f32_16x16x32_f16(ah, bl, sacc[nt], 0, 0, 0);
            }
        }
        float mk[4];
        #pragma unroll
        for (int nt = 0; nt < 4; nt++) mk[nt] = mask[b * S_ + k0 + nt * 16 + l16];

        // ---- online softmax (4 rows per thread: wm+quad*4+r), write P split to LDS
        #pragma unroll
        for (int r = 0; r < 4; r++) {
            float s[4];
            float rmax = -1e30f;
            #pragma unroll
            for (int nt = 0; nt < 4; nt++) {
                s[nt] = sacc[nt][r] * 0.125f + mk[nt];
                rmax = fmaxf(rmax, s[nt]);
            }
            #pragma unroll
            for (int off = 1; off < 16; off <<= 1) rmax = fmaxf(rmax, __shfl_xor(rmax, off));
            const float mnew = fmaxf(mrun[r], rmax);
            const float alpha = __expf(mrun[r] - mnew);
            const int row = wm + quad * 4 + r;
            float rsum = 0.f;
            #pragma unroll
            for (int nt = 0; nt < 4; nt++) {
                float p = __expf(s[nt] - mnew);
                f16_t ph = (f16_t)p;
                Ph[row * FSTR + nt * 16 + l16] = ph;
                Pl[row * FSTR + nt * 16 + l16] = (f16_t)(p - (float)ph);
                rsum += p;
            }
            #pragma unroll
            for (int off = 1; off < 16; off <<= 1) rsum += __shfl_xor(rsum, off);
            lrun[r] = lrun[r] * alpha + rsum;
            mrun[r] = mnew;
            #pragma unroll
            for (int nt = 0; nt < 4; nt++) Oacc[nt][r] *= alpha;
        }
        __syncthreads();   // P visible

        // ---- O += P @ V  (A = P rows, B = V^T rows)
        #pragma unroll
        for (int ks = 0; ks < 64; ks += 32) {
            f16x8_t ah = *(f16x8_t*)&Ph[(wm + l16) * FSTR + ks + quad * 8];
            f16x8_t al = *(f16x8_t*)&Pl[(wm + l16) * FSTR + ks + quad * 8];
            #pragma unroll
            for (int nt = 0; nt < 4; nt++) {
                f16x8_t bh = *(f16x8_t*)&VTh[(nt * 16 + l16) * FSTR + ks + quad * 8];
                f16x8_t bl = *(f16x8_t*)&VTl[(nt * 16 + l16) * FSTR + ks + quad * 8];
                Oacc[nt] = __builtin_amdgcn_mfma_f32_16x16x32_f16(ah, bh, Oacc[nt], 0, 0, 0);
                Oacc[nt] = __builtin_amdgcn_mfma_f32_16x16x32_f16(al, bh, Oacc[nt], 0, 0, 0);
                Oacc[nt] = __builtin_amdgcn_mfma_f32_16x16x32_f16(ah, bl, Oacc[nt], 0, 0, 0);
            }
        }
    }

    const size_t cb = (size_t)b * S_ * D_ + (size_t)h * DH_;
    float invl[4];
    #pragma unroll
    for (int r = 0; r < 4; r++) invl[r] = 1.0f / lrun[r];
    #pragma unroll
    for (int nt = 0; nt < 4; nt++)
        #pragma unroll
        for (int r = 0; r < 4; r++)
            ctx[cb + (size_t)(q0 + wm + quad * 4 + r) * D_ + nt * 16 + l16] = Oacc[nt][r] * invl[r];
}

// ---------------- out[t] = LN(x[t] + y[t]) * g + b
__global__ __launch_bounds__(256) void add_ln_kernel(
    const float* __restrict__ x, const float* __restrict__ y,
    const float* __restrict__ g, const float* __restrict__ bb,
    float* __restrict__ out)
{
    const int t = blockIdx.x;
    const int tid = threadIdx.x;
    __shared__ float red[256];
    float vals[3];
    float lsum = 0.f;
    #pragma unroll
    for (int i = 0; i < 3; i++) {
        int c = tid + i * 256;
        float v = x[(size_t)t * D_ + c] + y[(size_t)t * D_ + c];
        vals[i] = v; lsum += v;
    }
    red[tid] = lsum; __syncthreads();
    for (int off = 128; off > 0; off >>= 1) { if (tid < off) red[tid] += red[tid + off]; __syncthreads(); }
    const float mu = red[0] * (1.0f / D_);
    __syncthreads();
    float lvar = 0.f;
    #pragma unroll
    for (int i = 0; i < 3; i++) { float d = vals[i] - mu; lvar += d * d; }
    red[tid] = lvar; __syncthreads();
    for (int off = 128; off > 0; off >>= 1) { if (tid < off) red[tid] += red[tid + off]; __syncthreads(); }
    const float rstd = rsqrtf(red[0] * (1.0f / D_) + 1e-12f);
    #pragma unroll
    for (int i = 0; i < 3; i++) {
        int c = tid + i * 256;
        out[(size_t)t * D_ + c] = (vals[i] - mu) * rstd * g[c] + bb[c];
    }
}

// ---------------- router: 1 wave per token
__global__ __launch_bounds__(64) void router_kernel(
    const float* __restrict__ att, const float* __restrict__ Wr,
    const float* __restrict__ br, float* __restrict__ gate, int* __restrict__ eidx)
{
    const int t = blockIdx.x;
    const int lane = threadIdx.x;
    float lg[E_] = {};
    for (int d = lane; d < D_; d += 64) {
        float xv = att[(size_t)t * D_ + d];
        #pragma unroll
        for (int e = 0; e < E_; e++) lg[e] += xv * Wr[d * E_ + e];
    }
    #pragma unroll
    for (int off = 32; off > 0; off >>= 1)
        #pragma unroll
        for (int e = 0; e < E_; e++) lg[e] += __shfl_down(lg[e], off);
    if (lane == 0) {
        float mx = -1e30f; int mi = 0;
        #pragma unroll
        for (int e = 0; e < E_; e++) {
            lg[e] += br[e];
            if (lg[e] > mx) { mx = lg[e]; mi = e; }
        }
        float ssum = 0.f;
        #pragma unroll
        for (int e = 0; e < E_; e++) ssum += expf(lg[e] - mx);
        gate[t] = 1.0f / ssum;
        eidx[t] = mi;
    }
}

// ---------------- position-within-expert scan (single block) + per-expert counts
__global__ __launch_bounds__(256) void pos_scan_kernel(
    const int* __restrict__ eidx, const float* __restrict__ gate,
    int* __restrict__ pos, float* __restrict__ scale, int* __restrict__ cnt_out)
{
    __shared__ int cnt[256][E_];
    const int tid = threadIdx.x;
    const int start = tid * (T_ / 256);
    int lc[E_] = {};
    for (int i = 0; i < T_ / 256; i++) lc[eidx[start + i]]++;
    #pragma unroll
    for (int e = 0; e < E_; e++) cnt[tid][e] = lc[e];
    __syncthreads();
    if (tid < E_) {
        int run = 0;
        for (int i = 0; i < 256; i++) { int c = cnt[i][tid]; cnt[i][tid] = run; run += c; }
        cnt_out[tid] = run;
    }
    __syncthreads();
    int off[E_];
    #pragma unroll
    for (int e = 0; e < E_; e++) off[e] = cnt[tid][e];
    for (int i = 0; i < T_ / 256; i++) {
        int tk = start + i;
        int e = eidx[tk];
        int p = off[e]++;
        bool keep = p < CAP_;
        pos[tk] = p < CAP_ - 1 ? p : CAP_ - 1;
        scale[tk] = keep ? gate[tk] : 0.0f;
    }
}

// ---------------- scatter kept tokens into per-expert bf16 buffers
__global__ __launch_bounds__(256) void scatter_kernel(
    const float* __restrict__ att, const int* __restrict__ eidx,
    const int* __restrict__ pos, const float* __restrict__ scale,
    bf16_t* __restrict__ buf)
{
    const int t = blockIdx.x;
    if (scale[t] == 0.0f) return;
    const int tid = threadIdx.x;
    const float* src = att + (size_t)t * D_;
    bf16_t* dst = buf + ((size_t)eidx[t] * CAP_ + pos[t]) * D_;
    for (int i = tid; i < D_; i += 256) dst[i] = (bf16_t)src[i];
}

// ---------------- gather (bf16 y) + residual + final LN
__global__ __launch_bounds__(256) void final_ln_kernel(
    const float* __restrict__ att, const bf16_t* __restrict__ y,
    const int* __restrict__ eidx, const int* __restrict__ pos,
    const float* __restrict__ scale,
    const float* __restrict__ g, const float* __restrict__ bb,
    float* __restrict__ out)
{
    const int t = blockIdx.x;
    const int tid = threadIdx.x;
    __shared__ float red[256];
    const float sc = scale[t];
    const bf16_t* yrow = y + ((size_t)eidx[t] * CAP_ + pos[t]) * D_;
    float vals[3];
    float lsum = 0.f;
    #pragma unroll
    for (int i = 0; i < 3; i++) {
        int c = tid + i * 256;
        float v = att[(size_t)t * D_ + c] + (float)yrow[c] * sc;
        vals[i] = v; lsum += v;
    }
    red[tid] = lsum; __syncthreads();
    for (int off = 128; off > 0; off >>= 1) { if (tid < off) red[tid] += red[tid + off]; __syncthreads(); }
    const float mu = red[0] * (1.0f / D_);
    __syncthreads();
    float lvar = 0.f;
    #pragma unroll
    for (int i = 0; i < 3; i++) { float d = vals[i] - mu; lvar += d * d; }
    red[tid] = lvar; __syncthreads();
    for (int off = 128; off > 0; off >>= 1) { if (tid < off) red[tid] += red[tid + off]; __syncthreads(); }
    const float rstd = rsqrtf(red[0] * (1.0f / D_) + 1e-12f);
    #pragma unroll
    for (int i = 0; i < 3; i++) {
        int c = tid + i * 256;
        out[(size_t)t * D_ + c] = (vals[i] - mu) * rstd * g[c] + bb[c];
    }
}

extern "C" void kernel_launch(void* const* d_in, const int* in_sizes, int n_in,
                              void* d_out, int out_size, void* d_ws, size_t ws_size,
                              hipStream_t stream) {
    const float* x     = (const float*)d_in[0];
    const float* mask  = (const float*)d_in[1];
    const float* Wq    = (const float*)d_in[2];
    const float* bq    = (const float*)d_in[3];
    const float* Wk    = (const float*)d_in[4];
    const float* bk    = (const float*)d_in[5];
    const float* Wv    = (const float*)d_in[6];
    const float* bv    = (const float*)d_in[7];
    const float* Wo    = (const float*)d_in[8];
    const float* bo    = (const float*)d_in[9];
    const float* ln1g  = (const float*)d_in[10];
    const float* ln1b  = (const float*)d_in[11];
    const float* Wr    = (const float*)d_in[12];
    const float* br    = (const float*)d_in[13];
    const float* W1    = (const float*)d_in[14];
    const float* b1    = (const float*)d_in[15];
    const float* W2    = (const float*)d_in[16];
    const float* b2    = (const float*)d_in[17];
    const float* ln2g  = (const float*)d_in[18];
    const float* ln2b  = (const float*)d_in[19];
    float* out = (float*)d_out;

    char* ws = (char*)d_ws;
    const size_t TDB = (size_t)T_ * D_ * 4;
    float* qkv_buf = (float*)(ws);                       // [T,2304] fp32 (3 TDB)
    float* ctx_buf = (float*)(ws + 3 * TDB);
    float* att_buf = (float*)(ws + 4 * TDB);
    char*  smallp  = ws + 5 * TDB;
    float* gate_b  = (float*)(smallp);
    int*   eidx_b  = (int*)(smallp + 32768);
    int*   pos_b   = (int*)(smallp + 2 * 32768);
    float* scale_b = (float*)(smallp + 3 * 32768);
    int*   cnt_b   = (int*)(smallp + 4 * 32768);
    bf16_t* buf_b  = (bf16_t*)(smallp + 4 * 32768 + 128);
    bf16_t* y_b    = (bf16_t*)((char*)buf_b + (size_t)E_ * CAP_ * D_ * 2);
    // overlays of the qkv..ctx region (dead after add_ln):
    bf16_t* W1T = (bf16_t*)(ws);
    bf16_t* W2T = (bf16_t*)(ws + (size_t)E_ * FF_ * D_ * 2);
    bf16_t* h_b = (bf16_t*)(ws + (size_t)2 * E_ * FF_ * D_ * 2);
    float* proj_b = qkv_buf;   // [T,D] reuse (qkv dead after flash)

    dim3 blk(256);
    // ---- attention path (fp32-equivalent precision — feeds the router)
    gemm3_f32_kernel<<<dim3(36, T_ / 128), blk, 0, stream>>>(
        x, Wq, Wk, Wv, bq, bk, bv, qkv_buf, D_, QKVSTR);
    flash_attn_mfma_kernel<<<dim3(S_ / 64, H_, B_), blk, 0, stream>>>(qkv_buf, mask, ctx_buf);
    gemm3_f32_kernel<<<dim3(12, T_ / 128), blk, 0, stream>>>(
        ctx_buf, Wo, Wo, Wo, bo, bo, bo, proj_b, D_, D_);
    add_ln_kernel<<<dim3(T_), blk, 0, stream>>>(x, proj_b, ln1g, ln1b, att_buf);
    // ---- routing (fp32)
    router_kernel<<<dim3(T_), dim3(64), 0, stream>>>(att_buf, Wr, br, gate_b, eidx_b);
    pos_scan_kernel<<<dim3(1), blk, 0, stream>>>(eidx_b, gate_b, pos_b, scale_b, cnt_b);
    // ---- weight transpose-casts into dead qkv..ctx region (safe after add_ln)
    transpose_cast_kernel<<<dim3(FF_ / 32, D_ / 32, E_), blk, 0, stream>>>(W1, W1T, D_, FF_);
    transpose_cast_kernel<<<dim3(D_ / 32, FF_ / 32, E_), blk, 0, stream>>>(W2, W2T, FF_, D_);
    // ---- expert buffers
    hipMemsetAsync(buf_b, 0, (size_t)E_ * CAP_ * D_ * 2, stream);
    scatter_kernel<<<dim3(T_), blk, 0, stream>>>(att_buf, eidx_b, pos_b, scale_b, buf_b);
    // ---- expert FFNs, bf16 MFMA, 2 experts per z-batch
    for (int bch = 0; bch < 4; bch++) {
        const int e0 = bch * 2;
        mfma_gemm_kernel<<<dim3(FF_ / 128, CAP_ / 128, 2), blk, 0, stream>>>(
            buf_b + (size_t)e0 * CAP_ * D_, W1T + (size_t)e0 * FF_ * D_,
            b1 + (size_t)e0 * FF_, h_b,
            cnt_b, e0, CAP_, FF_, D_,
            (long)CAP_ * D_, (long)FF_ * D_, (long)FF_, (long)CAP_ * FF_, 1);
        mfma_gemm_kernel<<<dim3(D_ / 128, CAP_ / 128, 2), blk, 0, stream>>>(
            h_b, W2T + (size_t)e0 * D_ * FF_,
            b2 + (size_t)e0 * D_, y_b + (size_t)e0 * CAP_ * D_,
            cnt_b, e0, CAP_, D_, FF_,
            (long)CAP_ * FF_, (long)D_ * FF_, (long)D_, (long)CAP_ * D_, 0);
    }
    // ---- gather + residual + LN2
    final_ln_kernel<<<dim3(T_), blk, 0, stream>>>(att_buf, y_b, eidx_b, pos_b, scale_b, ln2g, ln2b, out);
}